// Round 15
// baseline (448.289 us; speedup 1.0000x reference)
//
#include <hip/hip_runtime.h>
#include <hip/hip_bf16.h>
#include <math.h>

// B=2, T=1024, D=1024, H=8, Dh=128, L=11, conv=4; chunk C=64, 16 chunks/bh
#define SCALE_Q 0.08838834764831845f

typedef __bf16 bf16x8 __attribute__((ext_vector_type(8)));
typedef float f32x4 __attribute__((ext_vector_type(4)));

static __device__ __forceinline__ float sigm(float x){ return 1.f/(1.f+__expf(-x)); }
static __device__ __forceinline__ ushort f2b(float v){
  __hip_bfloat16 t = __float2bfloat16(v);
  return __builtin_bit_cast(ushort, t);
}
static __device__ __forceinline__ float b2f(ushort u){
  unsigned v = (unsigned)u << 16; return __builtin_bit_cast(float, v);
}

// ---------------- fused prep: z=0..4 transcast 5 weights; z=5,6 cast x; z=7 Wsm ----------------
__global__ __launch_bounds__(256) void prep_all(const float* __restrict__ Wq,
    const float* __restrict__ Wk, const float* __restrict__ Wv,
    const float* __restrict__ Wg, const float* __restrict__ Wo,
    const float* __restrict__ X, const float* __restrict__ Wb,
    const float* __restrict__ Wa, const float* __restrict__ Wl,
    ushort* __restrict__ Wt4, ushort* __restrict__ Wot,
    ushort* __restrict__ x16, float* __restrict__ Wsm)
{
  int z = blockIdx.z;
  int tid = threadIdx.x;
  int flat = blockIdx.y * 32 + blockIdx.x;          // 0..1023
  if (z < 5) {
    __shared__ float tile[32][36];
    const float* W = (z==0)?Wq:(z==1)?Wk:(z==2)?Wv:(z==3)?Wg:Wo;
    ushort* Wt = (z<4)? (Wt4 + (size_t)z*1048576) : Wot;
    int n0 = blockIdx.x*32, k0 = blockIdx.y*32;
    int r = tid >> 3, c4 = (tid & 7) << 2;
    *(float4*)&tile[r][c4] = *(const float4*)&W[(size_t)(k0 + r)*1024 + n0 + c4];
    __syncthreads();
    ushort4 o;
    o.x = f2b(tile[c4+0][r]); o.y = f2b(tile[c4+1][r]);
    o.z = f2b(tile[c4+2][r]); o.w = f2b(tile[c4+3][r]);
    *(ushort4*)&Wt[(size_t)(n0 + r)*1024 + k0 + c4] = o;
  } else if (z < 7) {
    int idx = (z-5)*262144 + flat*256 + tid;
    float4 v = *(const float4*)&X[(size_t)idx*4];
    ushort4 o; o.x=f2b(v.x); o.y=f2b(v.y); o.z=f2b(v.z); o.w=f2b(v.w);
    *(ushort4*)&x16[(size_t)idx*4] = o;
  } else {
    int idx = flat*256 + tid;
    if (idx < 1024*104) {
      int k = idx / 104, c = idx % 104;
      float v = (c < 8) ? Wb[k*8+c] : (c < 16) ? Wa[k*8+(c-8)] : Wl[k*88+(c-16)];
      Wsm[idx] = v;
    }
  }
}

// ---------------- bf16 MFMA GEMM, 3-stage prefetch, counted vmcnt, XCD swizzle ----------------
__global__ __launch_bounds__(256) void gemm_bf16(const ushort* __restrict__ A,
    const ushort* __restrict__ Bt, void* __restrict__ C0, float* __restrict__ C1,
    int M, int N, int K, int nsplit, int ld0, int ld1, int c0bf16)
{
  __shared__ ushort As[3][128*32];
  __shared__ ushort Bs[3][128*32];
  int tid = threadIdx.x;
  int gx = gridDim.x;
  int nwg = gx * gridDim.y;
  int id = blockIdx.y * gx + blockIdx.x;
  int id2 = (id & 7) * (nwg >> 3) + (id >> 3);
  int bm = (id2 / gx) * 128, bn = (id2 % gx) * 128;
  int wave = tid >> 6, lane = tid & 63;
  int wm = (wave >> 1) * 64, wn = (wave & 1) * 64;
  int l16 = lane & 15, kh = lane >> 4;
  f32x4 acc[4][4] = {};
  int rowA0 = tid >> 2, boA = (tid & 3) * 16;
  int niter = K >> 5;

  #pragma unroll
  for (int s = 0; s < 2; ++s) {
    int k0 = s << 5;
    #pragma unroll
    for (int j = 0; j < 2; ++j) {
      int row = rowA0 + j*64;
      const char* gA = (const char*)A + (((size_t)(bm+row)*K + k0)*2 + boA);
      const char* gB = (const char*)Bt + (((size_t)(bn+row)*K + k0)*2 + boA);
      __builtin_amdgcn_global_load_lds((const __attribute__((address_space(1))) unsigned*)gA,
        (__attribute__((address_space(3))) unsigned*)((char*)&As[s][0] + row*64 + boA), 16, 0, 0);
      __builtin_amdgcn_global_load_lds((const __attribute__((address_space(1))) unsigned*)gB,
        (__attribute__((address_space(3))) unsigned*)((char*)&Bs[s][0] + row*64 + boA), 16, 0, 0);
    }
  }
  asm volatile("s_waitcnt vmcnt(4)" ::: "memory");
  __builtin_amdgcn_s_barrier();
  __builtin_amdgcn_sched_barrier(0);
  for (int i = 0; i < niter; ++i) {
    int cur = i % 3;
    if (i + 2 < niter) {
      int k0 = (i+2) << 5;
      int nb = (i+2) % 3;
      char* al = (char*)&As[nb][0];
      char* bl = (char*)&Bs[nb][0];
      #pragma unroll
      for (int j = 0; j < 2; ++j) {
        int row = rowA0 + j*64;
        const char* gA = (const char*)A + (((size_t)(bm+row)*K + k0)*2 + boA);
        const char* gB = (const char*)Bt + (((size_t)(bn+row)*K + k0)*2 + boA);
        __builtin_amdgcn_global_load_lds((const __attribute__((address_space(1))) unsigned*)gA,
          (__attribute__((address_space(3))) unsigned*)(al + row*64 + boA), 16, 0, 0);
        __builtin_amdgcn_global_load_lds((const __attribute__((address_space(1))) unsigned*)gB,
          (__attribute__((address_space(3))) unsigned*)(bl + row*64 + boA), 16, 0, 0);
      }
    }
    bf16x8 af[4], bfr[4];
    #pragma unroll
    for (int ii = 0; ii < 4; ++ii)
      af[ii] = *(bf16x8*)((char*)&As[cur][0] + (wm + ii*16 + l16)*64 + kh*16);
    #pragma unroll
    for (int j = 0; j < 4; ++j)
      bfr[j] = *(bf16x8*)((char*)&Bs[cur][0] + (wn + j*16 + l16)*64 + kh*16);
    #pragma unroll
    for (int ii = 0; ii < 4; ++ii)
      #pragma unroll
      for (int j = 0; j < 4; ++j)
        acc[ii][j] = __builtin_amdgcn_mfma_f32_16x16x32_bf16(af[ii], bfr[j], acc[ii][j], 0, 0, 0);
    if (i + 1 < niter) {
      if (i + 2 < niter) {
        asm volatile("s_waitcnt vmcnt(4) lgkmcnt(0)" ::: "memory");
      } else {
        asm volatile("s_waitcnt vmcnt(0) lgkmcnt(0)" ::: "memory");
      }
      __builtin_amdgcn_s_barrier();
      __builtin_amdgcn_sched_barrier(0);
    }
  }
  int rg = lane >> 4;
  #pragma unroll
  for (int i = 0; i < 4; ++i) {
    #pragma unroll
    for (int j = 0; j < 4; ++j) {
      int col = bn + wn + j*16 + l16;
      #pragma unroll
      for (int r = 0; r < 4; ++r) {
        int row = bm + wm + i*16 + rg*4 + r;
        float v = acc[i][j][r];
        if (col < nsplit) {
          if (c0bf16) ((ushort*)C0)[(size_t)row*ld0 + col] = f2b(v);
          else        ((float*)C0)[(size_t)row*ld0 + col] = v;
        } else C1[(size_t)row*ld1 + (col - nsplit)] = v;
      }
    }
  }
}

// -------- full-K skinny GEMM: xs[M][104] = x[M][1024] @ Wsm[1024][104] --------
// 256 blocks x 8 rows; X staged in LDS, Ws streamed from L2 (426KB, resident).
__global__ __launch_bounds__(256) void skinny104f(const float* __restrict__ X,
    const float* __restrict__ Wsm, float* __restrict__ xs)
{
  __shared__ float XL[8][1032];
  int tid = threadIdx.x;
  int m0 = blockIdx.x << 3;
  #pragma unroll
  for (int j = 0; j < 8; ++j) {
    int s = tid + j*256;
    int row = s >> 8, c4 = (s & 255) << 2;
    *(float4*)&XL[row][c4] = *(const float4*)&X[(size_t)(m0 + row)*1024 + c4];
  }
  __syncthreads();
  int r = tid >> 5, lane = tid & 31;
  float a0=0.f, a1=0.f, a2=0.f, a3=0.f;
  const float* xr = &XL[r][0];
  for (int k = 0; k < 1024; ++k) {
    float xv = xr[k];
    const float* wr = &Wsm[(size_t)k*104];
    a0 += xv*wr[lane];
    a1 += xv*wr[lane+32];
    a2 += xv*wr[lane+64];
    if (lane < 8) a3 += xv*wr[lane+96];
  }
  size_t o = (size_t)(m0 + r)*104;
  xs[o+lane] = a0; xs[o+lane+32] = a1; xs[o+lane+64] = a2;
  if (lane < 8) xs[o+lane+96] = a3;
}

// -------- fused depthwise causal conv(4)+silu q/k/v, all-bf16 outputs --------
__global__ __launch_bounds__(256) void conv_fused(const ushort* __restrict__ Xall,
    const float* __restrict__ Wq, const float* __restrict__ Wk, const float* __restrict__ Wv,
    ushort* __restrict__ qb16, ushort* __restrict__ kb16, ushort* __restrict__ vb16, int ldx)
{
  int mode = blockIdx.y;
  const float* W = (mode==0)?Wq:(mode==1)?Wk:Wv;
  const ushort* X = Xall + mode*1024;
  int row = blockIdx.x;
  int b = row >> 10, t = row & 1023;
  int tid = threadIdx.x;
  int c0 = tid << 2;
  float w[4][4];
  #pragma unroll
  for (int c = 0; c < 4; ++c) {
    float4 wv = *(const float4*)&W[(c0 + c)*4];
    w[c][0]=wv.x; w[c][1]=wv.y; w[c][2]=wv.z; w[c][3]=wv.w;
  }
  float acc[4] = {0.f,0.f,0.f,0.f};
  #pragma unroll
  for (int j = 0; j < 4; ++j) {
    int tt = t - 3 + j;
    if (tt >= 0) {
      ushort4 xv = *(const ushort4*)&X[(size_t)(b*1024 + tt)*ldx + c0];
      acc[0] += w[0][j]*b2f(xv.x); acc[1] += w[1][j]*b2f(xv.y);
      acc[2] += w[2][j]*b2f(xv.z); acc[3] += w[3][j]*b2f(xv.w);
    }
  }
  #pragma unroll
  for (int c = 0; c < 4; ++c) acc[c] *= sigm(acc[c]);
  if (mode < 2) {
    float ss = acc[0]*acc[0]+acc[1]*acc[1]+acc[2]*acc[2]+acc[3]*acc[3];
    ss += __shfl_xor(ss, 1); ss += __shfl_xor(ss, 2); ss += __shfl_xor(ss, 4);
    ss += __shfl_xor(ss, 8); ss += __shfl_xor(ss, 16);
    float r = rsqrtf(ss + 1e-6f);
    if (mode == 0) r *= SCALE_Q;
    acc[0]*=r; acc[1]*=r; acc[2]*=r; acc[3]*=r;
  }
  size_t o = (size_t)(b*1024 + t)*1024 + c0;
  ushort* Y = (mode==0)?qb16:(mode==1)?kb16:vb16;
  ushort4 yb; yb.x=f2b(acc[0]); yb.y=f2b(acc[1]); yb.z=f2b(acc[2]); yb.w=f2b(acc[3]);
  *(ushort4*)&Y[o] = yb;
}

// -------- per-(b,h) log-decay cumsum, one block per bh --------
__global__ __launch_bounds__(256) void gc2(const float* __restrict__ xs,
    const float* __restrict__ A_log, const float* __restrict__ dt_bias,
    float* __restrict__ gc)
{
  int bh = blockIdx.x, b = bh >> 3, h = bh & 7;
  __shared__ float sc[256];
  int tid = threadIdx.x;
  float aexp = __expf(A_log[h]), db = dt_bias[h];
  int t0 = tid*4;
  float g[4], csum = 0.f;
  #pragma unroll
  for (int z = 0; z < 4; ++z) {
    float zv = xs[(size_t)(b*1024 + t0 + z)*104 + 8 + h] + db;
    float sp = (zv > 20.f) ? zv : log1pf(__expf(zv));
    csum += -aexp*sp;
    g[z] = csum;
  }
  sc[tid] = csum;
  __syncthreads();
  for (int ofs = 1; ofs < 256; ofs <<= 1) {
    float v = (tid >= ofs) ? sc[tid-ofs] : 0.f;
    __syncthreads();
    sc[tid] += v;
    __syncthreads();
  }
  float excl = sc[tid] - csum;
  #pragma unroll
  for (int z = 0; z < 4; ++z) gc[bh*1024 + t0 + z] = excl + g[z];
}

// -------- chunk prep: bf16 K/V inputs, f32 solve; emits w f32, -Wk bf16, KpT bf16 --------
__global__ __launch_bounds__(256) void chunk_prep(const ushort* __restrict__ Kg16,
    const ushort* __restrict__ Vg16, const float* __restrict__ xs,
    const float* __restrict__ gcg, float* __restrict__ cw, ushort* __restrict__ cWk16,
    ushort* __restrict__ cKpT16, float* __restrict__ eD)
{
  int blk = blockIdx.x;
  int bh = blk >> 4, ck = blk & 15;
  int b = bh >> 3, h = bh & 7;
  int a = ck << 6;
  __shared__ float Kc[64][132];
  __shared__ float As[64][68];
  __shared__ float gcl[65];
  __shared__ float bl[64];
  __shared__ float egc[64];
  __shared__ float edt[64];
  int tid = threadIdx.x;
  for (int e = tid; e < 64*32; e += 256) {
    int t = e >> 5, c4 = (e & 31) << 2;
    ushort4 kv = *(const ushort4*)&Kg16[(size_t)(b*1024 + a + t)*1024 + h*128 + c4];
    Kc[t][c4+0] = b2f(kv.x); Kc[t][c4+1] = b2f(kv.y);
    Kc[t][c4+2] = b2f(kv.z); Kc[t][c4+3] = b2f(kv.w);
  }
  if (tid < 64) {
    gcl[tid] = gcg[bh*1024 + a + tid];
    bl[tid] = sigm(xs[(size_t)(b*1024 + a + tid)*104 + h]);
  }
  if (tid == 64) gcl[64] = (ck < 15) ? gcg[bh*1024 + a + 64] : 0.f;
  __syncthreads();
  if (tid < 64) {
    egc[tid] = __expf(gcl[tid] - gcl[0]);
    edt[tid] = (ck < 15) ? __expf(gcl[64] - gcl[tid]) : 0.f;
  }
  {
    int ti = tid >> 4, si = tid & 15;
    if (si <= ti) {
      float dot[4][4] = {};
      for (int kk = 0; kk < 128; kk += 4) {
        float4 kt[4], ks[4];
        #pragma unroll
        for (int z = 0; z < 4; ++z) kt[z] = *(float4*)&Kc[ti*4+z][kk];
        #pragma unroll
        for (int z = 0; z < 4; ++z) ks[z] = *(float4*)&Kc[si*4+z][kk];
        #pragma unroll
        for (int i = 0; i < 4; ++i)
          #pragma unroll
          for (int j = 0; j < 4; ++j)
            dot[i][j] += kt[i].x*ks[j].x + kt[i].y*ks[j].y + kt[i].z*ks[j].z + kt[i].w*ks[j].w;
      }
      #pragma unroll
      for (int i = 0; i < 4; ++i) {
        int t = ti*4 + i;
        #pragma unroll
        for (int j = 0; j < 4; ++j) {
          int s = si*4 + j;
          if (s < t) As[t][s] = bl[t]*dot[i][j]*__expf(gcl[t]-gcl[s]);
        }
      }
    }
  }
  __syncthreads();
  int c = tid;
  float u[64];
  if (c < 128) {
    #pragma unroll
    for (int t = 0; t < 64; ++t)
      u[t] = bl[t]*b2f(Vg16[(size_t)(b*1024 + a + t)*1024 + h*128 + c]);
  } else {
    int d = c - 128;
    #pragma unroll
    for (int t = 0; t < 64; ++t)
      u[t] = bl[t]*egc[t]*Kc[t][d];
  }
  #pragma unroll
  for (int t = 1; t < 64; ++t) {
    float acc = u[t];
    int s = 0;
    #pragma unroll
    for (; s + 4 <= t; s += 4) {
      float4 a4 = *(float4*)&As[t][s];
      acc -= a4.x*u[s] + a4.y*u[s+1] + a4.z*u[s+2] + a4.w*u[s+3];
    }
    #pragma unroll
    for (; s < t; ++s) acc -= As[t][s]*u[s];
    u[t] = acc;
  }
  size_t cbase = (size_t)blk*8192;
  if (c < 128) {
    #pragma unroll
    for (int t = 0; t < 64; ++t)
      cw[cbase + t*128 + c] = u[t];
  } else {
    int d = c - 128;
    #pragma unroll
    for (int t = 0; t < 64; ++t) {
      cWk16[cbase + t*128 + d] = f2b(-u[t]);
      cKpT16[cbase + d*64 + t] = f2b(Kc[t][d]*edt[t]);
    }
  }
  if (tid == 0) eD[blk] = (ck < 15) ? __expf(gcl[64]-gcl[0]) : 0.f;
}

// -------- chunk scan v6: MFMA both phases. 256 blocks = 16 e-slices(8) x 16 bh --------
__global__ __launch_bounds__(256) void chunk_scan6(const float* __restrict__ cw,
    const ushort* __restrict__ cWk16, const ushort* __restrict__ cKpT16,
    const float* __restrict__ eD, ushort* __restrict__ Ut)
{
  int blk = blockIdx.x;
  int slice = blk >> 4, bh = blk & 15;
  int e_base = slice << 3;
  __shared__ ushort Wks[2][8192];
  __shared__ ushort Kps[2][8192];
  __shared__ ushort StT[16*128];
  __shared__ ushort usT[16*64];
  __shared__ float  Stf[128*16];
  int tid = threadIdx.x;
  int wave = tid >> 6, lane = tid & 63;
  int l15 = lane & 15, kh = lane >> 4;
  for (int idx = tid; idx < 16*128; idx += 256) StT[idx] = 0;
  for (int idx = tid; idx < 16*64; idx += 256) usT[idx] = 0;
  for (int idx = tid; idx < 128*16; idx += 256) Stf[idx] = 0.f;

  int e = l15;
  int t0 = wave*16 + kh*4;
  int ci0 = bh << 4;
  f32x4 wcur = {0.f,0.f,0.f,0.f};
  if (e < 8) {
    #pragma unroll
    for (int r = 0; r < 4; ++r)
      wcur[r] = cw[(size_t)ci0*8192 + (t0+r)*128 + e_base + e];
  }
  {
    const char* wg = (const char*)(cWk16 + (size_t)ci0*8192);
    const char* kg = (const char*)(cKpT16 + (size_t)ci0*8192);
    #pragma unroll
    for (int j = 0; j < 4; ++j) {
      unsigned off = (j<<12) + (tid<<4);
      unsigned wrow = off >> 8, wslot = (off >> 4) & 15;
      unsigned wsrc = wrow*256 + ((wslot ^ (wrow & 15)) << 4);
      __builtin_amdgcn_global_load_lds((const __attribute__((address_space(1))) unsigned*)(wg + wsrc),
        (__attribute__((address_space(3))) unsigned*)((char*)&Wks[0][0] + off), 16, 0, 0);
      unsigned krow = off >> 7, kslot = (off >> 4) & 7;
      unsigned ksrc = krow*128 + ((kslot ^ (krow & 7)) << 4);
      __builtin_amdgcn_global_load_lds((const __attribute__((address_space(1))) unsigned*)(kg + ksrc),
        (__attribute__((address_space(3))) unsigned*)((char*)&Kps[0][0] + off), 16, 0, 0);
    }
  }
  __syncthreads();

  for (int i = 0; i < 16; ++i) {
    int ci = ci0 + i, a = i << 6, cur = i & 1;
    f32x4 wnext = {0.f,0.f,0.f,0.f};
    if (i < 15) {
      if (e < 8) {
        #pragma unroll
        for (int r = 0; r < 4; ++r)
          wnext[r] = cw[(size_t)(ci+1)*8192 + (t0+r)*128 + e_base + e];
      }
      const char* wg = (const char*)(cWk16 + (size_t)(ci+1)*8192);
      const char* kg = (const char*)(cKpT16 + (size_t)(ci+1)*8192);
      char* wl = (char*)&Wks[cur^1][0];
      char* kl = (char*)&Kps[cur^1][0];
      #pragma unroll
      for (int j = 0; j < 4; ++j) {
        unsigned off = (j<<12) + (tid<<4);
        unsigned wrow = off >> 8, wslot = (off >> 4) & 15;
        unsigned wsrc = wrow*256 + ((wslot ^ (wrow & 15)) << 4);
        __builtin_amdgcn_global_load_lds((const __attribute__((address_space(1))) unsigned*)(wg + wsrc),
          (__attribute__((address_space(3))) unsigned*)(wl + off), 16, 0, 0);
        unsigned krow = off >> 7, kslot = (off >> 4) & 7;
        unsigned ksrc = krow*128 + ((kslot ^ (krow & 7)) << 4);
        __builtin_amdgcn_global_load_lds((const __attribute__((address_space(1))) unsigned*)(kg + ksrc),
          (__attribute__((address_space(3))) unsigned*)(kl + off), 16, 0, 0);
      }
    }
    {
      f32x4 d = wcur;
      const char* wkb = (const char*)&Wks[cur][0];
      int arow = wave*16 + l15;
      #pragma unroll
      for (int ks = 0; ks < 4; ++ks) {
        bf16x8 afr = *(const bf16x8*)(wkb + arow*256 + (((ks*4 + kh) ^ l15) << 4));
        bf16x8 bfr = *(const bf16x8*)((const char*)StT + l15*256 + (((ks*4 + kh) ^ l15) << 4));
        d = __builtin_amdgcn_mfma_f32_16x16x32_bf16(afr, bfr, d, 0, 0, 0);
      }
      if (e < 8) {
        ushort4 uw;
        uw.x = f2b(d[0]); uw.y = f2b(d[1]); uw.z = f2b(d[2]); uw.w = f2b(d[3]);
        *(ushort4*)((char*)usT + e*128 + (((t0>>3) ^ (e&7)) << 4) + (t0&7)*2) = uw;
        *(ushort4*)&Ut[(size_t)(bh*128 + e_base + e)*1024 + a + t0] = uw;
      }
    }
    asm volatile("s_waitcnt lgkmcnt(0)" ::: "memory");
    __builtin_amdgcn_s_barrier();
    __builtin_amdgcn_sched_barrier(0);
    if (i < 15) {
      float ed = eD[ci];
      const char* kpb = (const char*)&Kps[cur][0];
      #pragma unroll
      for (int mt = 0; mt < 2; ++mt) {
        int krow = (wave*2 + mt)*16 + l15;
        int k0 = (wave*2 + mt)*16 + kh*4;
        f32x4 c;
        #pragma unroll
        for (int r = 0; r < 4; ++r) c[r] = ed * Stf[(k0+r)*16 + e];
        #pragma unroll
        for (int ts = 0; ts < 2; ++ts) {
          bf16x8 afr = *(const bf16x8*)(kpb + krow*128 + (((ts*4 + kh) ^ (krow&7)) << 4));
          bf16x8 bfr = *(const bf16x8*)((const char*)usT + l15*128 + (((ts*4 + kh) ^ (l15&7)) << 4));
          c = __builtin_amdgcn_mfma_f32_16x16x32_bf16(afr, bfr, c, 0, 0, 0);
        }
        #pragma unroll
        for (int r = 0; r < 4; ++r) Stf[(k0+r)*16 + e] = c[r];
        if (e < 8) {
          ushort4 sw;
          sw.x = f2b(c[0]); sw.y = f2b(c[1]); sw.z = f2b(c[2]); sw.w = f2b(c[3]);
          *(ushort4*)((char*)StT + e*256 + (((k0>>3) ^ e) << 4) + (k0&7)*2) = sw;
        }
      }
      wcur = wnext;
      asm volatile("s_waitcnt vmcnt(0) lgkmcnt(0)" ::: "memory");
      __builtin_amdgcn_s_barrier();
      __builtin_amdgcn_sched_barrier(0);
    }
  }
}

// -------- MFMA log-linear readout v3: LDS-staged K/Ut, double-buffered --------
__global__ __launch_bounds__(256) void readout3(const ushort* __restrict__ Qb,
    const ushort* __restrict__ Kb, const ushort* __restrict__ Ut,
    const float* __restrict__ gcg, const float* __restrict__ xs,
    float* __restrict__ Og)
{
  int blk = blockIdx.x;
  int bh = blk >> 4, ic = blk & 15;
  int half = blockIdx.y;
  int b = bh >> 3, h = bh & 7;
  int tbase = ic << 6;
  __shared__ ushort Ks[2][8192];
  __shared__ ushort Us[2][8192];
  __shared__ ushort Pl[4][1024];
  __shared__ float lamS[64][12];
  int tid = threadIdx.x;
  int wave = tid >> 6, lane = tid & 63;
  int l15 = lane & 15, kh = lane >> 4;

  const char* kgb = (const char*)Kb + ((size_t)(b*1024)*1024 + h*128)*2;
  const char* ugb = (const char*)Ut + ((size_t)(bh*128)*1024)*2;

  for (int e = tid; e < 64*11; e += 256) {
    int t = e/11, l = e%11;
    lamS[t][l] = sigm(xs[(size_t)(b*1024+tbase+t)*104 + 16 + h*11 + l]);
  }
  int tl = kh*4;
  float gct_r[4];
  #pragma unroll
  for (int r = 0; r < 4; ++r) gct_r[r] = gcg[bh*1024 + tbase + wave*16 + tl + r];
  bf16x8 qf[4];
  {
    const ushort* qp = &Qb[(size_t)(b*1024 + tbase + wave*16 + l15)*1024 + h*128 + kh*8];
    #pragma unroll
    for (int kk = 0; kk < 4; ++kk) qf[kk] = *(const bf16x8*)(qp + kk*32);
  }

  f32x4 accO[8] = {};
  int nsteps = ic + 1;
  int jmid = (nsteps + 1) >> 1;
  int j0 = half ? jmid : 0;
  int j1 = half ? nsteps : jmid;
  ushort* Pw = &Pl[wave][0];

  if (j0 < j1) {
    {
      const char* kg = kgb + (size_t)(j0<<6)*2048;
      const char* ug = ugb + (size_t)(j0<<6)*2;
      #pragma unroll
      for (int it = 0; it < 4; ++it) {
        unsigned off = (it<<12) + (tid<<4);
        unsigned krow = off >> 8, kc = (off >> 4) & 15;
        unsigned ksrc = krow*2048 + ((kc ^ (krow & 15)) << 4);
        __builtin_amdgcn_global_load_lds((const __attribute__((address_space(1))) unsigned*)(kg + ksrc),
          (__attribute__((address_space(3))) unsigned*)((char*)&Ks[0][0] + off), 16, 0, 0);
        unsigned ud = off >> 7, uc = (off >> 4) & 7;
        unsigned usrc = ud*2048 + ((uc ^ (ud & 7)) << 4);
        __builtin_amdgcn_global_load_lds((const __attribute__((address_space(1))) unsigned*)(ug + usrc),
          (__attribute__((address_space(3))) unsigned*)((char*)&Us[0][0] + off), 16, 0, 0);
      }
    }
    __syncthreads();
    int cur = 0;
    for (int j = j0; j < j1; ++j) {
      int sbase = j << 6;
      if (j + 1 < j1) {
        const char* kg = kgb + (size_t)((j+1)<<6)*2048;
        const char* ug = ugb + (size_t)((j+1)<<6)*2;
        char* kl = (char*)&Ks[cur^1][0];
        char* ul = (char*)&Us[cur^1][0];
        #pragma unroll
        for (int it = 0; it < 4; ++it) {
          unsigned off = (it<<12) + (tid<<4);
          unsigned krow = off >> 8, kc = (off >> 4) & 15;
          unsigned ksrc = krow*2048 + ((kc ^ (krow & 15)) << 4);
          __builtin_amdgcn_global_load_lds((const __attribute__((address_space(1))) unsigned*)(kg + ksrc),
            (__attribute__((address_space(3))) unsigned*)(kl + off), 16, 0, 0);
          unsigned ud = off >> 7, uc = (off >> 4) & 7;
          unsigned usrc = ud*2048 + ((uc ^ (ud & 7)) << 4);
          __builtin_amdgcn_global_load_lds((const __attribute__((address_space(1))) unsigned*)(ug + usrc),
            (__attribute__((address_space(3))) unsigned*)(ul + off), 16, 0, 0);
        }
      }
      float gcs_r[4];
      #pragma unroll
      for (int jt = 0; jt < 4; ++jt)
        gcs_r[jt] = gcg[bh*1024 + sbase + jt*16 + l15];
      f32x4 accS[4] = {};
      const char* ksb = (const char*)&Ks[cur][0];
      #pragma unroll
      for (int jt = 0; jt < 4; ++jt) {
        int row = jt*16 + l15;
        int rsw = row & 15;
        #pragma unroll
        for (int kk = 0; kk < 4; ++kk) {
          bf16x8 kf = *(const bf16x8*)(ksb + row*256 + (((kk*4 + kh) ^ rsw) << 4));
          accS[jt] = __builtin_amdgcn_mfma_f32_16x16x32_bf16(qf[kk], kf, accS[jt], 0, 0, 0);
        }
      }
      #pragma unroll
      for (int jt = 0; jt < 4; ++jt) {
        int sg = sbase + jt*16 + l15;
        #pragma unroll
        for (int r = 0; r < 4; ++r) {
          int t_loc = tl + r;
          int tg = tbase + wave*16 + t_loc;
          float pv = 0.f;
          if (sg <= tg) {
            int lev = 31 - __clz((unsigned)((tg+1) ^ sg));
            lev = lev > 10 ? 10 : lev;
            pv = accS[jt][r] * __expf(gct_r[r] - gcs_r[jt]) * lamS[wave*16 + t_loc][lev];
          }
          int bo = (t_loc << 7) + ((jt*16 + l15) << 1);
          bo ^= (t_loc & 7) << 4;
          *(ushort*)((char*)Pw + bo) = f2b(pv);
        }
      }
      const char* usb = (const char*)&Us[cur][0];
      #pragma unroll
      for (int ks = 0; ks < 2; ++ks) {
        int bo = (l15 << 7) + ((ks*32 + kh*8) << 1);
        bo ^= (l15 & 7) << 4;
        bf16x8 pa = *(bf16x8*)((char*)Pw + bo);
        #pragma unroll
        for (int dt = 0; dt < 8; ++dt) {
          int d = dt*16 + l15;
          bf16x8 uf = *(const bf16x8*)(usb + d*128 + (((ks*4 + kh) ^ (d & 7)) << 4));
          accO[dt] = __builtin_amdgcn_mfma_f32_16x16x32_bf16(pa, uf, accO[dt], 0, 0, 0);
        }
      }
      __syncthreads();
      cur ^= 1;
    }
  }
  float* og = Og + (size_t)half*2097152;
  #pragma unroll
  for (int dt = 0; dt < 8; ++dt) {
    #pragma unroll
    for (int r = 0; r < 4; ++r) {
      int row = tbase + wave*16 + tl + r;
      og[(size_t)(b*1024 + row)*1024 + h*128 + dt*16 + l15] = accO[dt][r];
    }
  }
}

// -------- gated RMSNorm (sums two partial O buffers) -> bf16 --------
__global__ __launch_bounds__(64) void normgate(const float* __restrict__ O1,
    const float* __restrict__ O2, const float* __restrict__ G,
    const float* __restrict__ norm_w, ushort* __restrict__ Y)
{
  int row = blockIdx.x;
  int lane = threadIdx.x;
  size_t base = (size_t)(row >> 3)*1024 + (size_t)(row & 7)*128;
  float2 oa = *(const float2*)&O1[base + lane*2];
  float2 ob = *(const float2*)&O2[base + lane*2];
  float ox = oa.x + ob.x, oy = oa.y + ob.y;
  float ss = ox*ox + oy*oy;
  #pragma unroll
  for (int m = 1; m < 64; m <<= 1) ss += __shfl_xor(ss, m);
  float r = rsqrtf(ss * (1.f/128.f) + 1e-5f);
  float2 g = *(const float2*)&G[base + lane*2];
  ushort2 y;
  y.x = f2b(ox * r * norm_w[lane*2+0] * (g.x * sigm(g.x)));
  y.y = f2b(oy * r * norm_w[lane*2+1] * (g.y * sigm(g.y)));
  *(ushort2*)&Y[base + lane*2] = y;
}

extern "C" void kernel_launch(void* const* d_in, const int* in_sizes, int n_in,
                              void* d_out, int out_size, void* d_ws, size_t ws_size,
                              hipStream_t stream)
{
  const float* x    = (const float*)d_in[0];
  const float* Wq   = (const float*)d_in[3];
  const float* Wk   = (const float*)d_in[4];
  const float* Wv   = (const float*)d_in[5];
  const float* Wb   = (const float*)d_in[6];
  const float* Wa   = (const float*)d_in[7];
  const float* Wl   = (const float*)d_in[8];
  const float* Wg   = (const float*)d_in[9];
  const float* Wo   = (const float*)d_in[10];
  const float* cq   = (const float*)d_in[11];
  const float* ck   = (const float*)d_in[12];
  const float* cv   = (const float*)d_in[13];
  const float* A_log   = (const float*)d_in[14];
  const float* dt_bias = (const float*)d_in[15];
  const float* norm_w  = (const float*)d_in[16];
  float* out = (float*)d_out;

  float* p = (float*)d_ws;
  float* xqkv = p;  p += 6291456;            // region reused: qkv bf16 then cw/cWk16/cKpT16
  float* xg   = p;  p += 2097152;
  float* kbu  = p;  p += 2097152;            // (spare)
  float* vbu  = p;  p += 2097152;            // vb16 lives here
  float* o1   = p;  p += 2097152;            // o1,o2 MUST be adjacent (readout3 half offset)
  float* o2   = p;  p += 2097152;
  float* xs   = p;  p += 212992;
  float* gc   = p;  p += 16384;
  float* eD   = p;  p += 256;
  ushort* x16 = (ushort*)p; p += 1048576;    // [2048][1024] bf16
  ushort* Wt4 = (ushort*)p; p += 2097152;    // [4096][1024] bf16
  ushort* Wot = (ushort*)p; p += 524288;     // [1024][1024] bf16
  float* Wsm  = p;  p += 106496;
  ushort* yb16= (ushort*)p; p += 1048576;    // [2048][1024] bf16
  ushort* qb16= (ushort*)p; p += 1048576;    // [2048][1024] bf16
  ushort* kb16= (ushort*)p; p += 1048576;    // [2048][1024] bf16
  ushort* ut16= (ushort*)p; p += 1048576;    // [16*128][1024] bf16
  ushort* xqkv16 = (ushort*)xqkv;            // [2048][3072] bf16 (12MB)
  ushort* vb16 = (ushort*)vbu;               // [2048][1024] bf16
  float* cw  = xqkv;                          // overlays after convs
  ushort* cWk16  = (ushort*)(xqkv + 2097152);
  ushort* cKpT16 = (ushort*)(xqkv + 3145728);
  (void)kbu;

  dim3 blk(256);
  prep_all<<<dim3(32,32,8), blk, 0, stream>>>(Wq, Wk, Wv, Wg, Wo, x, Wb, Wa, Wl,
                                              Wt4, Wot, x16, Wsm);
  gemm_bf16<<<dim3(32,16), blk, 0, stream>>>(x16, Wt4, xqkv16, xg, 2048, 4096, 1024,
                                             3072, 3072, 1024, 1);
  skinny104f<<<dim3(256), blk, 0, stream>>>(x, Wsm, xs);
  conv_fused<<<dim3(2048,3), blk, 0, stream>>>(xqkv16, cq, ck, cv, qb16, kb16, vb16, 3072);
  gc2<<<dim3(16), blk, 0, stream>>>(xs, A_log, dt_bias, gc);
  chunk_prep<<<dim3(256), blk, 0, stream>>>(kb16, vb16, xs, gc, cw, cWk16, cKpT16, eD);
  chunk_scan6<<<dim3(256), blk, 0, stream>>>(cw, cWk16, cKpT16, eD, ut16);
  readout3<<<dim3(256,2), blk, 0, stream>>>(qb16, kb16, ut16, gc, xs, o1);
  normgate<<<dim3(16384), dim3(64), 0, stream>>>(o1, o2, xg, norm_w, yb16);
  gemm_bf16<<<dim3(8,16), blk, 0, stream>>>(yb16, Wot, out, out, 2048, 1024, 1024,
                                            1024, 1024, 1024, 0);
}

// Round 16
// 197.108 us; speedup vs baseline: 2.2743x; 2.2743x over previous
//
#include <hip/hip_runtime.h>
#include <hip/hip_bf16.h>
#include <math.h>

// B=2, T=1024, D=1024, H=8, Dh=128, L=11, conv=4; chunk C=64, 16 chunks/bh
#define SCALE_Q 0.08838834764831845f

typedef __bf16 bf16x8 __attribute__((ext_vector_type(8)));
typedef float f32x4 __attribute__((ext_vector_type(4)));

static __device__ __forceinline__ float sigm(float x){ return 1.f/(1.f+__expf(-x)); }
static __device__ __forceinline__ ushort f2b(float v){
  __hip_bfloat16 t = __float2bfloat16(v);
  return __builtin_bit_cast(ushort, t);
}
static __device__ __forceinline__ float b2f(ushort u){
  unsigned v = (unsigned)u << 16; return __builtin_bit_cast(float, v);
}

// ---------------- fused prep: z=0..4 transcast 5 weights; z=5,6 cast x; z=7 Wsm ----------------
__global__ __launch_bounds__(256) void prep_all(const float* __restrict__ Wq,
    const float* __restrict__ Wk, const float* __restrict__ Wv,
    const float* __restrict__ Wg, const float* __restrict__ Wo,
    const float* __restrict__ X, const float* __restrict__ Wb,
    const float* __restrict__ Wa, const float* __restrict__ Wl,
    ushort* __restrict__ Wt4, ushort* __restrict__ Wot,
    ushort* __restrict__ x16, float* __restrict__ Wsm)
{
  int z = blockIdx.z;
  int tid = threadIdx.x;
  int flat = blockIdx.y * 32 + blockIdx.x;          // 0..1023
  if (z < 5) {
    __shared__ float tile[32][36];
    const float* W = (z==0)?Wq:(z==1)?Wk:(z==2)?Wv:(z==3)?Wg:Wo;
    ushort* Wt = (z<4)? (Wt4 + (size_t)z*1048576) : Wot;
    int n0 = blockIdx.x*32, k0 = blockIdx.y*32;
    int r = tid >> 3, c4 = (tid & 7) << 2;
    *(float4*)&tile[r][c4] = *(const float4*)&W[(size_t)(k0 + r)*1024 + n0 + c4];
    __syncthreads();
    ushort4 o;
    o.x = f2b(tile[c4+0][r]); o.y = f2b(tile[c4+1][r]);
    o.z = f2b(tile[c4+2][r]); o.w = f2b(tile[c4+3][r]);
    *(ushort4*)&Wt[(size_t)(n0 + r)*1024 + k0 + c4] = o;
  } else if (z < 7) {
    int idx = (z-5)*262144 + flat*256 + tid;
    float4 v = *(const float4*)&X[(size_t)idx*4];
    ushort4 o; o.x=f2b(v.x); o.y=f2b(v.y); o.z=f2b(v.z); o.w=f2b(v.w);
    *(ushort4*)&x16[(size_t)idx*4] = o;
  } else {
    int idx = flat*256 + tid;
    if (idx < 1024*104) {
      int k = idx / 104, c = idx % 104;
      float v = (c < 8) ? Wb[k*8+c] : (c < 16) ? Wa[k*8+(c-8)] : Wl[k*88+(c-16)];
      Wsm[idx] = v;
    }
  }
}

// ---------------- bf16 MFMA GEMM, 3-stage prefetch, counted vmcnt, XCD swizzle ----------------
__global__ __launch_bounds__(256) void gemm_bf16(const ushort* __restrict__ A,
    const ushort* __restrict__ Bt, void* __restrict__ C0, float* __restrict__ C1,
    int M, int N, int K, int nsplit, int ld0, int ld1, int c0bf16)
{
  __shared__ ushort As[3][128*32];
  __shared__ ushort Bs[3][128*32];
  int tid = threadIdx.x;
  int gx = gridDim.x;
  int nwg = gx * gridDim.y;
  int id = blockIdx.y * gx + blockIdx.x;
  int id2 = (id & 7) * (nwg >> 3) + (id >> 3);
  int bm = (id2 / gx) * 128, bn = (id2 % gx) * 128;
  int wave = tid >> 6, lane = tid & 63;
  int wm = (wave >> 1) * 64, wn = (wave & 1) * 64;
  int l16 = lane & 15, kh = lane >> 4;
  f32x4 acc[4][4] = {};
  int rowA0 = tid >> 2, boA = (tid & 3) * 16;
  int niter = K >> 5;

  #pragma unroll
  for (int s = 0; s < 2; ++s) {
    int k0 = s << 5;
    #pragma unroll
    for (int j = 0; j < 2; ++j) {
      int row = rowA0 + j*64;
      const char* gA = (const char*)A + (((size_t)(bm+row)*K + k0)*2 + boA);
      const char* gB = (const char*)Bt + (((size_t)(bn+row)*K + k0)*2 + boA);
      __builtin_amdgcn_global_load_lds((const __attribute__((address_space(1))) unsigned*)gA,
        (__attribute__((address_space(3))) unsigned*)((char*)&As[s][0] + row*64 + boA), 16, 0, 0);
      __builtin_amdgcn_global_load_lds((const __attribute__((address_space(1))) unsigned*)gB,
        (__attribute__((address_space(3))) unsigned*)((char*)&Bs[s][0] + row*64 + boA), 16, 0, 0);
    }
  }
  asm volatile("s_waitcnt vmcnt(4)" ::: "memory");
  __builtin_amdgcn_s_barrier();
  __builtin_amdgcn_sched_barrier(0);
  for (int i = 0; i < niter; ++i) {
    int cur = i % 3;
    if (i + 2 < niter) {
      int k0 = (i+2) << 5;
      int nb = (i+2) % 3;
      char* al = (char*)&As[nb][0];
      char* bl = (char*)&Bs[nb][0];
      #pragma unroll
      for (int j = 0; j < 2; ++j) {
        int row = rowA0 + j*64;
        const char* gA = (const char*)A + (((size_t)(bm+row)*K + k0)*2 + boA);
        const char* gB = (const char*)Bt + (((size_t)(bn+row)*K + k0)*2 + boA);
        __builtin_amdgcn_global_load_lds((const __attribute__((address_space(1))) unsigned*)gA,
          (__attribute__((address_space(3))) unsigned*)(al + row*64 + boA), 16, 0, 0);
        __builtin_amdgcn_global_load_lds((const __attribute__((address_space(1))) unsigned*)gB,
          (__attribute__((address_space(3))) unsigned*)(bl + row*64 + boA), 16, 0, 0);
      }
    }
    bf16x8 af[4], bfr[4];
    #pragma unroll
    for (int ii = 0; ii < 4; ++ii)
      af[ii] = *(bf16x8*)((char*)&As[cur][0] + (wm + ii*16 + l16)*64 + kh*16);
    #pragma unroll
    for (int j = 0; j < 4; ++j)
      bfr[j] = *(bf16x8*)((char*)&Bs[cur][0] + (wn + j*16 + l16)*64 + kh*16);
    #pragma unroll
    for (int ii = 0; ii < 4; ++ii)
      #pragma unroll
      for (int j = 0; j < 4; ++j)
        acc[ii][j] = __builtin_amdgcn_mfma_f32_16x16x32_bf16(af[ii], bfr[j], acc[ii][j], 0, 0, 0);
    if (i + 1 < niter) {
      if (i + 2 < niter) {
        asm volatile("s_waitcnt vmcnt(4) lgkmcnt(0)" ::: "memory");
      } else {
        asm volatile("s_waitcnt vmcnt(0) lgkmcnt(0)" ::: "memory");
      }
      __builtin_amdgcn_s_barrier();
      __builtin_amdgcn_sched_barrier(0);
    }
  }
  int rg = lane >> 4;
  #pragma unroll
  for (int i = 0; i < 4; ++i) {
    #pragma unroll
    for (int j = 0; j < 4; ++j) {
      int col = bn + wn + j*16 + l16;
      #pragma unroll
      for (int r = 0; r < 4; ++r) {
        int row = bm + wm + i*16 + rg*4 + r;
        float v = acc[i][j][r];
        if (col < nsplit) {
          if (c0bf16) ((ushort*)C0)[(size_t)row*ld0 + col] = f2b(v);
          else        ((float*)C0)[(size_t)row*ld0 + col] = v;
        } else C1[(size_t)row*ld1 + (col - nsplit)] = v;
      }
    }
  }
}

// -------- skinny split-K GEMM: part[ks][M][104] = x[M,k0:k0+128] @ Wsm[k0:k0+128][104] --------
__global__ __launch_bounds__(256) void skinny104(const float* __restrict__ X,
    const float* __restrict__ Wsm, float* __restrict__ part)
{
  __shared__ float XL[64][132];
  __shared__ float WsL[128][112];
  int tid = threadIdx.x;
  int m0 = blockIdx.x << 6;
  int k0 = blockIdx.y << 7;
  #pragma unroll
  for (int j = 0; j < 8; ++j) {
    int s = tid + j*256;
    int row = s >> 5, c4 = (s & 31) << 2;
    *(float4*)&XL[row][c4] = *(const float4*)&X[(size_t)(m0 + row)*1024 + k0 + c4];
  }
  {
    int k = tid >> 1, c = 104 + ((tid & 1) << 2);
    *(float4*)&WsL[k][c] = (float4){0.f,0.f,0.f,0.f};
  }
  {
    int k = tid >> 1, cb = (tid & 1) * 52;
    #pragma unroll
    for (int j = 0; j < 13; ++j) {
      *(float4*)&WsL[k][cb + j*4] = *(const float4*)&Wsm[(size_t)(k0 + k)*104 + cb + j*4];
    }
  }
  __syncthreads();
  int row = tid >> 2, cq = tid & 3;
  int cbase = cq * 28;
  f32x4 acc[7] = {};
  const float* xrow = &XL[row][0];
  #pragma unroll 4
  for (int k = 0; k < 128; ++k) {
    float xv = xrow[k];
    const f32x4* wr = (const f32x4*)&WsL[k][cbase];
    #pragma unroll
    for (int j = 0; j < 7; ++j) acc[j] += xv * wr[j];
  }
  float* pr = &part[((size_t)blockIdx.y*2048 + m0 + row)*104 + cbase];
  int nst = (cq == 3) ? 5 : 7;
  for (int j = 0; j < nst; ++j) *(f32x4*)&pr[j*4] = acc[j];
}

// -------- reduce 8 K-slice partials -> xs[2048][104] --------
__global__ __launch_bounds__(256) void reduce8(const float* __restrict__ part,
    float* __restrict__ xs)
{
  int idx = blockIdx.x*256 + threadIdx.x;   // 833*256 == 213248 >= 2048*104
  if (idx >= 212992) return;
  float s = 0.f;
  #pragma unroll
  for (int i = 0; i < 8; ++i) s += part[(size_t)i*212992 + idx];
  xs[idx] = s;
}

// -------- fused depthwise causal conv(4)+silu q/k/v, all-bf16 outputs --------
__global__ __launch_bounds__(256) void conv_fused(const ushort* __restrict__ Xall,
    const float* __restrict__ Wq, const float* __restrict__ Wk, const float* __restrict__ Wv,
    ushort* __restrict__ qb16, ushort* __restrict__ kb16, ushort* __restrict__ vb16, int ldx)
{
  int mode = blockIdx.y;
  const float* W = (mode==0)?Wq:(mode==1)?Wk:Wv;
  const ushort* X = Xall + mode*1024;
  int row = blockIdx.x;
  int b = row >> 10, t = row & 1023;
  int tid = threadIdx.x;
  int c0 = tid << 2;
  float w[4][4];
  #pragma unroll
  for (int c = 0; c < 4; ++c) {
    float4 wv = *(const float4*)&W[(c0 + c)*4];
    w[c][0]=wv.x; w[c][1]=wv.y; w[c][2]=wv.z; w[c][3]=wv.w;
  }
  float acc[4] = {0.f,0.f,0.f,0.f};
  #pragma unroll
  for (int j = 0; j < 4; ++j) {
    int tt = t - 3 + j;
    if (tt >= 0) {
      ushort4 xv = *(const ushort4*)&X[(size_t)(b*1024 + tt)*ldx + c0];
      acc[0] += w[0][j]*b2f(xv.x); acc[1] += w[1][j]*b2f(xv.y);
      acc[2] += w[2][j]*b2f(xv.z); acc[3] += w[3][j]*b2f(xv.w);
    }
  }
  #pragma unroll
  for (int c = 0; c < 4; ++c) acc[c] *= sigm(acc[c]);
  if (mode < 2) {
    float ss = acc[0]*acc[0]+acc[1]*acc[1]+acc[2]*acc[2]+acc[3]*acc[3];
    ss += __shfl_xor(ss, 1); ss += __shfl_xor(ss, 2); ss += __shfl_xor(ss, 4);
    ss += __shfl_xor(ss, 8); ss += __shfl_xor(ss, 16);
    float r = rsqrtf(ss + 1e-6f);
    if (mode == 0) r *= SCALE_Q;
    acc[0]*=r; acc[1]*=r; acc[2]*=r; acc[3]*=r;
  }
  size_t o = (size_t)(b*1024 + t)*1024 + c0;
  ushort* Y = (mode==0)?qb16:(mode==1)?kb16:vb16;
  ushort4 yb; yb.x=f2b(acc[0]); yb.y=f2b(acc[1]); yb.z=f2b(acc[2]); yb.w=f2b(acc[3]);
  *(ushort4*)&Y[o] = yb;
}

// -------- per-(b,h) log-decay cumsum, one block per bh --------
__global__ __launch_bounds__(256) void gc2(const float* __restrict__ xs,
    const float* __restrict__ A_log, const float* __restrict__ dt_bias,
    float* __restrict__ gc)
{
  int bh = blockIdx.x, b = bh >> 3, h = bh & 7;
  __shared__ float sc[256];
  int tid = threadIdx.x;
  float aexp = __expf(A_log[h]), db = dt_bias[h];
  int t0 = tid*4;
  float g[4], csum = 0.f;
  #pragma unroll
  for (int z = 0; z < 4; ++z) {
    float zv = xs[(size_t)(b*1024 + t0 + z)*104 + 8 + h] + db;
    float sp = (zv > 20.f) ? zv : log1pf(__expf(zv));
    csum += -aexp*sp;
    g[z] = csum;
  }
  sc[tid] = csum;
  __syncthreads();
  for (int ofs = 1; ofs < 256; ofs <<= 1) {
    float v = (tid >= ofs) ? sc[tid-ofs] : 0.f;
    __syncthreads();
    sc[tid] += v;
    __syncthreads();
  }
  float excl = sc[tid] - csum;
  #pragma unroll
  for (int z = 0; z < 4; ++z) gc[bh*1024 + t0 + z] = excl + g[z];
}

// -------- chunk prep: bf16 K/V inputs, f32 solve; emits w f32, -Wk bf16, KpT bf16 --------
__global__ __launch_bounds__(256) void chunk_prep(const ushort* __restrict__ Kg16,
    const ushort* __restrict__ Vg16, const float* __restrict__ xs,
    const float* __restrict__ gcg, float* __restrict__ cw, ushort* __restrict__ cWk16,
    ushort* __restrict__ cKpT16, float* __restrict__ eD)
{
  int blk = blockIdx.x;
  int bh = blk >> 4, ck = blk & 15;
  int b = bh >> 3, h = bh & 7;
  int a = ck << 6;
  __shared__ float Kc[64][132];
  __shared__ float As[64][68];
  __shared__ float gcl[65];
  __shared__ float bl[64];
  __shared__ float egc[64];
  __shared__ float edt[64];
  int tid = threadIdx.x;
  for (int e = tid; e < 64*32; e += 256) {
    int t = e >> 5, c4 = (e & 31) << 2;
    ushort4 kv = *(const ushort4*)&Kg16[(size_t)(b*1024 + a + t)*1024 + h*128 + c4];
    Kc[t][c4+0] = b2f(kv.x); Kc[t][c4+1] = b2f(kv.y);
    Kc[t][c4+2] = b2f(kv.z); Kc[t][c4+3] = b2f(kv.w);
  }
  if (tid < 64) {
    gcl[tid] = gcg[bh*1024 + a + tid];
    bl[tid] = sigm(xs[(size_t)(b*1024 + a + tid)*104 + h]);
  }
  if (tid == 64) gcl[64] = (ck < 15) ? gcg[bh*1024 + a + 64] : 0.f;
  __syncthreads();
  if (tid < 64) {
    egc[tid] = __expf(gcl[tid] - gcl[0]);
    edt[tid] = (ck < 15) ? __expf(gcl[64] - gcl[tid]) : 0.f;
  }
  {
    int ti = tid >> 4, si = tid & 15;
    if (si <= ti) {
      float dot[4][4] = {};
      for (int kk = 0; kk < 128; kk += 4) {
        float4 kt[4], ks[4];
        #pragma unroll
        for (int z = 0; z < 4; ++z) kt[z] = *(float4*)&Kc[ti*4+z][kk];
        #pragma unroll
        for (int z = 0; z < 4; ++z) ks[z] = *(float4*)&Kc[si*4+z][kk];
        #pragma unroll
        for (int i = 0; i < 4; ++i)
          #pragma unroll
          for (int j = 0; j < 4; ++j)
            dot[i][j] += kt[i].x*ks[j].x + kt[i].y*ks[j].y + kt[i].z*ks[j].z + kt[i].w*ks[j].w;
      }
      #pragma unroll
      for (int i = 0; i < 4; ++i) {
        int t = ti*4 + i;
        #pragma unroll
        for (int j = 0; j < 4; ++j) {
          int s = si*4 + j;
          if (s < t) As[t][s] = bl[t]*dot[i][j]*__expf(gcl[t]-gcl[s]);
        }
      }
    }
  }
  __syncthreads();
  int c = tid;
  float u[64];
  if (c < 128) {
    #pragma unroll
    for (int t = 0; t < 64; ++t)
      u[t] = bl[t]*b2f(Vg16[(size_t)(b*1024 + a + t)*1024 + h*128 + c]);
  } else {
    int d = c - 128;
    #pragma unroll
    for (int t = 0; t < 64; ++t)
      u[t] = bl[t]*egc[t]*Kc[t][d];
  }
  #pragma unroll
  for (int t = 1; t < 64; ++t) {
    float acc = u[t];
    int s = 0;
    #pragma unroll
    for (; s + 4 <= t; s += 4) {
      float4 a4 = *(float4*)&As[t][s];
      acc -= a4.x*u[s] + a4.y*u[s+1] + a4.z*u[s+2] + a4.w*u[s+3];
    }
    #pragma unroll
    for (; s < t; ++s) acc -= As[t][s]*u[s];
    u[t] = acc;
  }
  size_t cbase = (size_t)blk*8192;
  if (c < 128) {
    #pragma unroll
    for (int t = 0; t < 64; ++t)
      cw[cbase + t*128 + c] = u[t];
  } else {
    int d = c - 128;
    #pragma unroll
    for (int t = 0; t < 64; ++t) {
      cWk16[cbase + t*128 + d] = f2b(-u[t]);
      cKpT16[cbase + d*64 + t] = f2b(Kc[t][d]*edt[t]);
    }
  }
  if (tid == 0) eD[blk] = (ck < 15) ? __expf(gcl[64]-gcl[0]) : 0.f;
}

// -------- chunk scan v6: MFMA both phases. 256 blocks = 16 e-slices(8) x 16 bh --------
__global__ __launch_bounds__(256) void chunk_scan6(const float* __restrict__ cw,
    const ushort* __restrict__ cWk16, const ushort* __restrict__ cKpT16,
    const float* __restrict__ eD, ushort* __restrict__ Ut)
{
  int blk = blockIdx.x;
  int slice = blk >> 4, bh = blk & 15;
  int e_base = slice << 3;
  __shared__ ushort Wks[2][8192];
  __shared__ ushort Kps[2][8192];
  __shared__ ushort StT[16*128];
  __shared__ ushort usT[16*64];
  __shared__ float  Stf[128*16];
  int tid = threadIdx.x;
  int wave = tid >> 6, lane = tid & 63;
  int l15 = lane & 15, kh = lane >> 4;
  for (int idx = tid; idx < 16*128; idx += 256) StT[idx] = 0;
  for (int idx = tid; idx < 16*64; idx += 256) usT[idx] = 0;
  for (int idx = tid; idx < 128*16; idx += 256) Stf[idx] = 0.f;

  int e = l15;
  int t0 = wave*16 + kh*4;
  int ci0 = bh << 4;
  f32x4 wcur = {0.f,0.f,0.f,0.f};
  if (e < 8) {
    #pragma unroll
    for (int r = 0; r < 4; ++r)
      wcur[r] = cw[(size_t)ci0*8192 + (t0+r)*128 + e_base + e];
  }
  {
    const char* wg = (const char*)(cWk16 + (size_t)ci0*8192);
    const char* kg = (const char*)(cKpT16 + (size_t)ci0*8192);
    #pragma unroll
    for (int j = 0; j < 4; ++j) {
      unsigned off = (j<<12) + (tid<<4);
      unsigned wrow = off >> 8, wslot = (off >> 4) & 15;
      unsigned wsrc = wrow*256 + ((wslot ^ (wrow & 15)) << 4);
      __builtin_amdgcn_global_load_lds((const __attribute__((address_space(1))) unsigned*)(wg + wsrc),
        (__attribute__((address_space(3))) unsigned*)((char*)&Wks[0][0] + off), 16, 0, 0);
      unsigned krow = off >> 7, kslot = (off >> 4) & 7;
      unsigned ksrc = krow*128 + ((kslot ^ (krow & 7)) << 4);
      __builtin_amdgcn_global_load_lds((const __attribute__((address_space(1))) unsigned*)(kg + ksrc),
        (__attribute__((address_space(3))) unsigned*)((char*)&Kps[0][0] + off), 16, 0, 0);
    }
  }
  __syncthreads();

  for (int i = 0; i < 16; ++i) {
    int ci = ci0 + i, a = i << 6, cur = i & 1;
    f32x4 wnext = {0.f,0.f,0.f,0.f};
    if (i < 15) {
      if (e < 8) {
        #pragma unroll
        for (int r = 0; r < 4; ++r)
          wnext[r] = cw[(size_t)(ci+1)*8192 + (t0+r)*128 + e_base + e];
      }
      const char* wg = (const char*)(cWk16 + (size_t)(ci+1)*8192);
      const char* kg = (const char*)(cKpT16 + (size_t)(ci+1)*8192);
      char* wl = (char*)&Wks[cur^1][0];
      char* kl = (char*)&Kps[cur^1][0];
      #pragma unroll
      for (int j = 0; j < 4; ++j) {
        unsigned off = (j<<12) + (tid<<4);
        unsigned wrow = off >> 8, wslot = (off >> 4) & 15;
        unsigned wsrc = wrow*256 + ((wslot ^ (wrow & 15)) << 4);
        __builtin_amdgcn_global_load_lds((const __attribute__((address_space(1))) unsigned*)(wg + wsrc),
          (__attribute__((address_space(3))) unsigned*)(wl + off), 16, 0, 0);
        unsigned krow = off >> 7, kslot = (off >> 4) & 7;
        unsigned ksrc = krow*128 + ((kslot ^ (krow & 7)) << 4);
        __builtin_amdgcn_global_load_lds((const __attribute__((address_space(1))) unsigned*)(kg + ksrc),
          (__attribute__((address_space(3))) unsigned*)(kl + off), 16, 0, 0);
      }
    }
    {
      f32x4 d = wcur;
      const char* wkb = (const char*)&Wks[cur][0];
      int arow = wave*16 + l15;
      #pragma unroll
      for (int ks = 0; ks < 4; ++ks) {
        bf16x8 afr = *(const bf16x8*)(wkb + arow*256 + (((ks*4 + kh) ^ l15) << 4));
        bf16x8 bfr = *(const bf16x8*)((const char*)StT + l15*256 + (((ks*4 + kh) ^ l15) << 4));
        d = __builtin_amdgcn_mfma_f32_16x16x32_bf16(afr, bfr, d, 0, 0, 0);
      }
      if (e < 8) {
        ushort4 uw;
        uw.x = f2b(d[0]); uw.y = f2b(d[1]); uw.z = f2b(d[2]); uw.w = f2b(d[3]);
        *(ushort4*)((char*)usT + e*128 + (((t0>>3) ^ (e&7)) << 4) + (t0&7)*2) = uw;
        *(ushort4*)&Ut[(size_t)(bh*128 + e_base + e)*1024 + a + t0] = uw;
      }
    }
    asm volatile("s_waitcnt lgkmcnt(0)" ::: "memory");
    __builtin_amdgcn_s_barrier();
    __builtin_amdgcn_sched_barrier(0);
    if (i < 15) {
      float ed = eD[ci];
      const char* kpb = (const char*)&Kps[cur][0];
      #pragma unroll
      for (int mt = 0; mt < 2; ++mt) {
        int krow = (wave*2 + mt)*16 + l15;
        int k0 = (wave*2 + mt)*16 + kh*4;
        f32x4 c;
        #pragma unroll
        for (int r = 0; r < 4; ++r) c[r] = ed * Stf[(k0+r)*16 + e];
        #pragma unroll
        for (int ts = 0; ts < 2; ++ts) {
          bf16x8 afr = *(const bf16x8*)(kpb + krow*128 + (((ts*4 + kh) ^ (krow&7)) << 4));
          bf16x8 bfr = *(const bf16x8*)((const char*)usT + l15*128 + (((ts*4 + kh) ^ (l15&7)) << 4));
          c = __builtin_amdgcn_mfma_f32_16x16x32_bf16(afr, bfr, c, 0, 0, 0);
        }
        #pragma unroll
        for (int r = 0; r < 4; ++r) Stf[(k0+r)*16 + e] = c[r];
        if (e < 8) {
          ushort4 sw;
          sw.x = f2b(c[0]); sw.y = f2b(c[1]); sw.z = f2b(c[2]); sw.w = f2b(c[3]);
          *(ushort4*)((char*)StT + e*256 + (((k0>>3) ^ e) << 4) + (k0&7)*2) = sw;
        }
      }
      wcur = wnext;
      asm volatile("s_waitcnt vmcnt(0) lgkmcnt(0)" ::: "memory");
      __builtin_amdgcn_s_barrier();
      __builtin_amdgcn_sched_barrier(0);
    }
  }
}

// -------- MFMA log-linear readout v3: LDS-staged K/Ut, double-buffered --------
__global__ __launch_bounds__(256) void readout3(const ushort* __restrict__ Qb,
    const ushort* __restrict__ Kb, const ushort* __restrict__ Ut,
    const float* __restrict__ gcg, const float* __restrict__ xs,
    float* __restrict__ Og)
{
  int blk = blockIdx.x;
  int bh = blk >> 4, ic = blk & 15;
  int half = blockIdx.y;
  int b = bh >> 3, h = bh & 7;
  int tbase = ic << 6;
  __shared__ ushort Ks[2][8192];
  __shared__ ushort Us[2][8192];
  __shared__ ushort Pl[4][1024];
  __shared__ float lamS[64][12];
  int tid = threadIdx.x;
  int wave = tid >> 6, lane = tid & 63;
  int l15 = lane & 15, kh = lane >> 4;

  const char* kgb = (const char*)Kb + ((size_t)(b*1024)*1024 + h*128)*2;
  const char* ugb = (const char*)Ut + ((size_t)(bh*128)*1024)*2;

  for (int e = tid; e < 64*11; e += 256) {
    int t = e/11, l = e%11;
    lamS[t][l] = sigm(xs[(size_t)(b*1024+tbase+t)*104 + 16 + h*11 + l]);
  }
  int tl = kh*4;
  float gct_r[4];
  #pragma unroll
  for (int r = 0; r < 4; ++r) gct_r[r] = gcg[bh*1024 + tbase + wave*16 + tl + r];
  bf16x8 qf[4];
  {
    const ushort* qp = &Qb[(size_t)(b*1024 + tbase + wave*16 + l15)*1024 + h*128 + kh*8];
    #pragma unroll
    for (int kk = 0; kk < 4; ++kk) qf[kk] = *(const bf16x8*)(qp + kk*32);
  }

  f32x4 accO[8] = {};
  int nsteps = ic + 1;
  int jmid = (nsteps + 1) >> 1;
  int j0 = half ? jmid : 0;
  int j1 = half ? nsteps : jmid;
  ushort* Pw = &Pl[wave][0];

  if (j0 < j1) {
    {
      const char* kg = kgb + (size_t)(j0<<6)*2048;
      const char* ug = ugb + (size_t)(j0<<6)*2;
      #pragma unroll
      for (int it = 0; it < 4; ++it) {
        unsigned off = (it<<12) + (tid<<4);
        unsigned krow = off >> 8, kc = (off >> 4) & 15;
        unsigned ksrc = krow*2048 + ((kc ^ (krow & 15)) << 4);
        __builtin_amdgcn_global_load_lds((const __attribute__((address_space(1))) unsigned*)(kg + ksrc),
          (__attribute__((address_space(3))) unsigned*)((char*)&Ks[0][0] + off), 16, 0, 0);
        unsigned ud = off >> 7, uc = (off >> 4) & 7;
        unsigned usrc = ud*2048 + ((uc ^ (ud & 7)) << 4);
        __builtin_amdgcn_global_load_lds((const __attribute__((address_space(1))) unsigned*)(ug + usrc),
          (__attribute__((address_space(3))) unsigned*)((char*)&Us[0][0] + off), 16, 0, 0);
      }
    }
    __syncthreads();
    int cur = 0;
    for (int j = j0; j < j1; ++j) {
      int sbase = j << 6;
      if (j + 1 < j1) {
        const char* kg = kgb + (size_t)((j+1)<<6)*2048;
        const char* ug = ugb + (size_t)((j+1)<<6)*2;
        char* kl = (char*)&Ks[cur^1][0];
        char* ul = (char*)&Us[cur^1][0];
        #pragma unroll
        for (int it = 0; it < 4; ++it) {
          unsigned off = (it<<12) + (tid<<4);
          unsigned krow = off >> 8, kc = (off >> 4) & 15;
          unsigned ksrc = krow*2048 + ((kc ^ (krow & 15)) << 4);
          __builtin_amdgcn_global_load_lds((const __attribute__((address_space(1))) unsigned*)(kg + ksrc),
            (__attribute__((address_space(3))) unsigned*)(kl + off), 16, 0, 0);
          unsigned ud = off >> 7, uc = (off >> 4) & 7;
          unsigned usrc = ud*2048 + ((uc ^ (ud & 7)) << 4);
          __builtin_amdgcn_global_load_lds((const __attribute__((address_space(1))) unsigned*)(ug + usrc),
            (__attribute__((address_space(3))) unsigned*)(ul + off), 16, 0, 0);
        }
      }
      float gcs_r[4];
      #pragma unroll
      for (int jt = 0; jt < 4; ++jt)
        gcs_r[jt] = gcg[bh*1024 + sbase + jt*16 + l15];
      f32x4 accS[4] = {};
      const char* ksb = (const char*)&Ks[cur][0];
      #pragma unroll
      for (int jt = 0; jt < 4; ++jt) {
        int row = jt*16 + l15;
        int rsw = row & 15;
        #pragma unroll
        for (int kk = 0; kk < 4; ++kk) {
          bf16x8 kf = *(const bf16x8*)(ksb + row*256 + (((kk*4 + kh) ^ rsw) << 4));
          accS[jt] = __builtin_amdgcn_mfma_f32_16x16x32_bf16(qf[kk], kf, accS[jt], 0, 0, 0);
        }
      }
      #pragma unroll
      for (int jt = 0; jt < 4; ++jt) {
        int sg = sbase + jt*16 + l15;
        #pragma unroll
        for (int r = 0; r < 4; ++r) {
          int t_loc = tl + r;
          int tg = tbase + wave*16 + t_loc;
          float pv = 0.f;
          if (sg <= tg) {
            int lev = 31 - __clz((unsigned)((tg+1) ^ sg));
            lev = lev > 10 ? 10 : lev;
            pv = accS[jt][r] * __expf(gct_r[r] - gcs_r[jt]) * lamS[wave*16 + t_loc][lev];
          }
          int bo = (t_loc << 7) + ((jt*16 + l15) << 1);
          bo ^= (t_loc & 7) << 4;
          *(ushort*)((char*)Pw + bo) = f2b(pv);
        }
      }
      const char* usb = (const char*)&Us[cur][0];
      #pragma unroll
      for (int ks = 0; ks < 2; ++ks) {
        int bo = (l15 << 7) + ((ks*32 + kh*8) << 1);
        bo ^= (l15 & 7) << 4;
        bf16x8 pa = *(bf16x8*)((char*)Pw + bo);
        #pragma unroll
        for (int dt = 0; dt < 8; ++dt) {
          int d = dt*16 + l15;
          bf16x8 uf = *(const bf16x8*)(usb + d*128 + (((ks*4 + kh) ^ (d & 7)) << 4));
          accO[dt] = __builtin_amdgcn_mfma_f32_16x16x32_bf16(pa, uf, accO[dt], 0, 0, 0);
        }
      }
      __syncthreads();
      cur ^= 1;
    }
  }
  float* og = Og + (size_t)half*2097152;
  #pragma unroll
  for (int dt = 0; dt < 8; ++dt) {
    #pragma unroll
    for (int r = 0; r < 4; ++r) {
      int row = tbase + wave*16 + tl + r;
      og[(size_t)(b*1024 + row)*1024 + h*128 + dt*16 + l15] = accO[dt][r];
    }
  }
}

// -------- gated RMSNorm (sums two partial O buffers) -> bf16 --------
__global__ __launch_bounds__(64) void normgate(const float* __restrict__ O1,
    const float* __restrict__ O2, const float* __restrict__ G,
    const float* __restrict__ norm_w, ushort* __restrict__ Y)
{
  int row = blockIdx.x;
  int lane = threadIdx.x;
  size_t base = (size_t)(row >> 3)*1024 + (size_t)(row & 7)*128;
  float2 oa = *(const float2*)&O1[base + lane*2];
  float2 ob = *(const float2*)&O2[base + lane*2];
  float ox = oa.x + ob.x, oy = oa.y + ob.y;
  float ss = ox*ox + oy*oy;
  #pragma unroll
  for (int m = 1; m < 64; m <<= 1) ss += __shfl_xor(ss, m);
  float r = rsqrtf(ss * (1.f/128.f) + 1e-5f);
  float2 g = *(const float2*)&G[base + lane*2];
  ushort2 y;
  y.x = f2b(ox * r * norm_w[lane*2+0] * (g.x * sigm(g.x)));
  y.y = f2b(oy * r * norm_w[lane*2+1] * (g.y * sigm(g.y)));
  *(ushort2*)&Y[base + lane*2] = y;
}

extern "C" void kernel_launch(void* const* d_in, const int* in_sizes, int n_in,
                              void* d_out, int out_size, void* d_ws, size_t ws_size,
                              hipStream_t stream)
{
  const float* x    = (const float*)d_in[0];
  const float* Wq   = (const float*)d_in[3];
  const float* Wk   = (const float*)d_in[4];
  const float* Wv   = (const float*)d_in[5];
  const float* Wb   = (const float*)d_in[6];
  const float* Wa   = (const float*)d_in[7];
  const float* Wl   = (const float*)d_in[8];
  const float* Wg   = (const float*)d_in[9];
  const float* Wo   = (const float*)d_in[10];
  const float* cq   = (const float*)d_in[11];
  const float* ck   = (const float*)d_in[12];
  const float* cv   = (const float*)d_in[13];
  const float* A_log   = (const float*)d_in[14];
  const float* dt_bias = (const float*)d_in[15];
  const float* norm_w  = (const float*)d_in[16];
  float* out = (float*)d_out;

  float* p = (float*)d_ws;
  float* xqkv = p;  p += 6291456;            // region reused: qkv bf16 then cw/cWk16/cKpT16
  float* xg   = p;  p += 2097152;
  float* kbu  = p;  p += 2097152;            // (spare)
  float* vbu  = p;  p += 2097152;            // vb16 lives here
  float* o1   = p;  p += 2097152;            // o1,o2 MUST be adjacent (readout3 half offset)
  float* o2   = p;  p += 2097152;
  float* xs   = p;  p += 212992;
  float* gc   = p;  p += 16384;
  float* eD   = p;  p += 256;
  ushort* x16 = (ushort*)p; p += 1048576;    // [2048][1024] bf16
  ushort* Wt4 = (ushort*)p; p += 2097152;    // [4096][1024] bf16
  ushort* Wot = (ushort*)p; p += 524288;     // [1024][1024] bf16
  float* Wsm  = p;  p += 106496;
  ushort* yb16= (ushort*)p; p += 1048576;    // [2048][1024] bf16
  ushort* qb16= (ushort*)p; p += 1048576;    // [2048][1024] bf16
  ushort* kb16= (ushort*)p; p += 1048576;    // [2048][1024] bf16
  ushort* ut16= (ushort*)p; p += 1048576;    // [16*128][1024] bf16
  ushort* xqkv16 = (ushort*)xqkv;            // [2048][3072] bf16 (12MB)
  ushort* vb16 = (ushort*)vbu;               // [2048][1024] bf16
  float* cw  = xqkv;                          // overlays after convs
  ushort* cWk16  = (ushort*)(xqkv + 2097152);
  ushort* cKpT16 = (ushort*)(xqkv + 3145728);
  float* part = o1;                           // [8][2048][104] partials; o1 dead until readout3
  (void)kbu;

  dim3 blk(256);
  prep_all<<<dim3(32,32,8), blk, 0, stream>>>(Wq, Wk, Wv, Wg, Wo, x, Wb, Wa, Wl,
                                              Wt4, Wot, x16, Wsm);
  gemm_bf16<<<dim3(32,16), blk, 0, stream>>>(x16, Wt4, xqkv16, xg, 2048, 4096, 1024,
                                             3072, 3072, 1024, 1);
  skinny104<<<dim3(32,8), blk, 0, stream>>>(x, Wsm, part);
  reduce8<<<dim3(833), blk, 0, stream>>>(part, xs);
  conv_fused<<<dim3(2048,3), blk, 0, stream>>>(xqkv16, cq, ck, cv, qb16, kb16, vb16, 3072);
  gc2<<<dim3(16), blk, 0, stream>>>(xs, A_log, dt_bias, gc);
  chunk_prep<<<dim3(256), blk, 0, stream>>>(kb16, vb16, xs, gc, cw, cWk16, cKpT16, eD);
  chunk_scan6<<<dim3(256), blk, 0, stream>>>(cw, cWk16, cKpT16, eD, ut16);
  readout3<<<dim3(256,2), blk, 0, stream>>>(qb16, kb16, ut16, gc, xs, o1);
  normgate<<<dim3(16384), dim3(64), 0, stream>>>(o1, o2, xg, norm_w, yb16);
  gemm_bf16<<<dim3(8,16), blk, 0, stream>>>(yb16, Wot, out, out, 2048, 1024, 1024,
                                            1024, 1024, 1024, 0);
}

// Round 17
// 193.039 us; speedup vs baseline: 2.3223x; 1.0211x over previous
//
#include <hip/hip_runtime.h>
#include <hip/hip_bf16.h>
#include <math.h>

// B=2, T=1024, D=1024, H=8, Dh=128, L=11, conv=4; chunk C=64, 16 chunks/bh
#define SCALE_Q 0.08838834764831845f

typedef __bf16 bf16x8 __attribute__((ext_vector_type(8)));
typedef float f32x4 __attribute__((ext_vector_type(4)));

static __device__ __forceinline__ float sigm(float x){ return 1.f/(1.f+__expf(-x)); }
static __device__ __forceinline__ ushort f2b(float v){
  __hip_bfloat16 t = __float2bfloat16(v);
  return __builtin_bit_cast(ushort, t);
}
static __device__ __forceinline__ float b2f(ushort u){
  unsigned v = (unsigned)u << 16; return __builtin_bit_cast(float, v);
}

// ---------------- fused prep: z=0..4 transcast 5 weights; z=5,6 cast x; z=7 Wsm ----------------
__global__ __launch_bounds__(256) void prep_all(const float* __restrict__ Wq,
    const float* __restrict__ Wk, const float* __restrict__ Wv,
    const float* __restrict__ Wg, const float* __restrict__ Wo,
    const float* __restrict__ X, const float* __restrict__ Wb,
    const float* __restrict__ Wa, const float* __restrict__ Wl,
    ushort* __restrict__ Wt4, ushort* __restrict__ Wot,
    ushort* __restrict__ x16, float* __restrict__ Wsm)
{
  int z = blockIdx.z;
  int tid = threadIdx.x;
  int flat = blockIdx.y * 32 + blockIdx.x;          // 0..1023
  if (z < 5) {
    __shared__ float tile[32][36];
    const float* W = (z==0)?Wq:(z==1)?Wk:(z==2)?Wv:(z==3)?Wg:Wo;
    ushort* Wt = (z<4)? (Wt4 + (size_t)z*1048576) : Wot;
    int n0 = blockIdx.x*32, k0 = blockIdx.y*32;
    int r = tid >> 3, c4 = (tid & 7) << 2;
    *(float4*)&tile[r][c4] = *(const float4*)&W[(size_t)(k0 + r)*1024 + n0 + c4];
    __syncthreads();
    ushort4 o;
    o.x = f2b(tile[c4+0][r]); o.y = f2b(tile[c4+1][r]);
    o.z = f2b(tile[c4+2][r]); o.w = f2b(tile[c4+3][r]);
    *(ushort4*)&Wt[(size_t)(n0 + r)*1024 + k0 + c4] = o;
  } else if (z < 7) {
    int idx = (z-5)*262144 + flat*256 + tid;
    float4 v = *(const float4*)&X[(size_t)idx*4];
    ushort4 o; o.x=f2b(v.x); o.y=f2b(v.y); o.z=f2b(v.z); o.w=f2b(v.w);
    *(ushort4*)&x16[(size_t)idx*4] = o;
  } else {
    int idx = flat*256 + tid;
    if (idx < 1024*104) {
      int k = idx / 104, c = idx % 104;
      float v = (c < 8) ? Wb[k*8+c] : (c < 16) ? Wa[k*8+(c-8)] : Wl[k*88+(c-16)];
      Wsm[idx] = v;
    }
  }
}

// ---------------- bf16 MFMA GEMM, 3-stage prefetch, counted vmcnt, XCD swizzle ----------------
__global__ __launch_bounds__(256) void gemm_bf16(const ushort* __restrict__ A,
    const ushort* __restrict__ Bt, void* __restrict__ C0, float* __restrict__ C1,
    int M, int N, int K, int nsplit, int ld0, int ld1, int c0bf16)
{
  __shared__ ushort As[3][128*32];
  __shared__ ushort Bs[3][128*32];
  int tid = threadIdx.x;
  int gx = gridDim.x;
  int nwg = gx * gridDim.y;
  int id = blockIdx.y * gx + blockIdx.x;
  int id2 = (id & 7) * (nwg >> 3) + (id >> 3);
  int bm = (id2 / gx) * 128, bn = (id2 % gx) * 128;
  int wave = tid >> 6, lane = tid & 63;
  int wm = (wave >> 1) * 64, wn = (wave & 1) * 64;
  int l16 = lane & 15, kh = lane >> 4;
  f32x4 acc[4][4] = {};
  int rowA0 = tid >> 2, boA = (tid & 3) * 16;
  int niter = K >> 5;

  #pragma unroll
  for (int s = 0; s < 2; ++s) {
    int k0 = s << 5;
    #pragma unroll
    for (int j = 0; j < 2; ++j) {
      int row = rowA0 + j*64;
      const char* gA = (const char*)A + (((size_t)(bm+row)*K + k0)*2 + boA);
      const char* gB = (const char*)Bt + (((size_t)(bn+row)*K + k0)*2 + boA);
      __builtin_amdgcn_global_load_lds((const __attribute__((address_space(1))) unsigned*)gA,
        (__attribute__((address_space(3))) unsigned*)((char*)&As[s][0] + row*64 + boA), 16, 0, 0);
      __builtin_amdgcn_global_load_lds((const __attribute__((address_space(1))) unsigned*)gB,
        (__attribute__((address_space(3))) unsigned*)((char*)&Bs[s][0] + row*64 + boA), 16, 0, 0);
    }
  }
  asm volatile("s_waitcnt vmcnt(4)" ::: "memory");
  __builtin_amdgcn_s_barrier();
  __builtin_amdgcn_sched_barrier(0);
  for (int i = 0; i < niter; ++i) {
    int cur = i % 3;
    if (i + 2 < niter) {
      int k0 = (i+2) << 5;
      int nb = (i+2) % 3;
      char* al = (char*)&As[nb][0];
      char* bl = (char*)&Bs[nb][0];
      #pragma unroll
      for (int j = 0; j < 2; ++j) {
        int row = rowA0 + j*64;
        const char* gA = (const char*)A + (((size_t)(bm+row)*K + k0)*2 + boA);
        const char* gB = (const char*)Bt + (((size_t)(bn+row)*K + k0)*2 + boA);
        __builtin_amdgcn_global_load_lds((const __attribute__((address_space(1))) unsigned*)gA,
          (__attribute__((address_space(3))) unsigned*)(al + row*64 + boA), 16, 0, 0);
        __builtin_amdgcn_global_load_lds((const __attribute__((address_space(1))) unsigned*)gB,
          (__attribute__((address_space(3))) unsigned*)(bl + row*64 + boA), 16, 0, 0);
      }
    }
    bf16x8 af[4], bfr[4];
    #pragma unroll
    for (int ii = 0; ii < 4; ++ii)
      af[ii] = *(bf16x8*)((char*)&As[cur][0] + (wm + ii*16 + l16)*64 + kh*16);
    #pragma unroll
    for (int j = 0; j < 4; ++j)
      bfr[j] = *(bf16x8*)((char*)&Bs[cur][0] + (wn + j*16 + l16)*64 + kh*16);
    #pragma unroll
    for (int ii = 0; ii < 4; ++ii)
      #pragma unroll
      for (int j = 0; j < 4; ++j)
        acc[ii][j] = __builtin_amdgcn_mfma_f32_16x16x32_bf16(af[ii], bfr[j], acc[ii][j], 0, 0, 0);
    if (i + 1 < niter) {
      if (i + 2 < niter) {
        asm volatile("s_waitcnt vmcnt(4) lgkmcnt(0)" ::: "memory");
      } else {
        asm volatile("s_waitcnt vmcnt(0) lgkmcnt(0)" ::: "memory");
      }
      __builtin_amdgcn_s_barrier();
      __builtin_amdgcn_sched_barrier(0);
    }
  }
  int rg = lane >> 4;
  #pragma unroll
  for (int i = 0; i < 4; ++i) {
    #pragma unroll
    for (int j = 0; j < 4; ++j) {
      int col = bn + wn + j*16 + l16;
      #pragma unroll
      for (int r = 0; r < 4; ++r) {
        int row = bm + wm + i*16 + rg*4 + r;
        float v = acc[i][j][r];
        if (col < nsplit) {
          if (c0bf16) ((ushort*)C0)[(size_t)row*ld0 + col] = f2b(v);
          else        ((float*)C0)[(size_t)row*ld0 + col] = v;
        } else C1[(size_t)row*ld1 + (col - nsplit)] = v;
      }
    }
  }
}

// -------- skinny split-K GEMM: part[ks][M][104] = x[M,k0:k0+128] @ Wsm[k0:k0+128][104] --------
__global__ __launch_bounds__(256) void skinny104(const float* __restrict__ X,
    const float* __restrict__ Wsm, float* __restrict__ part)
{
  __shared__ float XL[64][132];
  __shared__ float WsL[128][112];
  int tid = threadIdx.x;
  int m0 = blockIdx.x << 6;
  int k0 = blockIdx.y << 7;
  #pragma unroll
  for (int j = 0; j < 8; ++j) {
    int s = tid + j*256;
    int row = s >> 5, c4 = (s & 31) << 2;
    *(float4*)&XL[row][c4] = *(const float4*)&X[(size_t)(m0 + row)*1024 + k0 + c4];
  }
  {
    int k = tid >> 1, c = 104 + ((tid & 1) << 2);
    *(float4*)&WsL[k][c] = (float4){0.f,0.f,0.f,0.f};
  }
  {
    int k = tid >> 1, cb = (tid & 1) * 52;
    #pragma unroll
    for (int j = 0; j < 13; ++j) {
      *(float4*)&WsL[k][cb + j*4] = *(const float4*)&Wsm[(size_t)(k0 + k)*104 + cb + j*4];
    }
  }
  __syncthreads();
  int row = tid >> 2, cq = tid & 3;
  int cbase = cq * 28;
  f32x4 acc[7] = {};
  const float* xrow = &XL[row][0];
  #pragma unroll 4
  for (int k = 0; k < 128; ++k) {
    float xv = xrow[k];
    const f32x4* wr = (const f32x4*)&WsL[k][cbase];
    #pragma unroll
    for (int j = 0; j < 7; ++j) acc[j] += xv * wr[j];
  }
  float* pr = &part[((size_t)blockIdx.y*2048 + m0 + row)*104 + cbase];
  int nst = (cq == 3) ? 5 : 7;
  for (int j = 0; j < nst; ++j) *(f32x4*)&pr[j*4] = acc[j];
}

// -------- reduce 8 K-slice partials -> xs[2048][104] --------
__global__ __launch_bounds__(256) void reduce8(const float* __restrict__ part,
    float* __restrict__ xs)
{
  int idx = blockIdx.x*256 + threadIdx.x;
  if (idx >= 212992) return;
  float s = 0.f;
  #pragma unroll
  for (int i = 0; i < 8; ++i) s += part[(size_t)i*212992 + idx];
  xs[idx] = s;
}

// -------- fused depthwise causal conv(4)+silu q/k/v, all-bf16 outputs --------
__global__ __launch_bounds__(256) void conv_fused(const ushort* __restrict__ Xall,
    const float* __restrict__ Wq, const float* __restrict__ Wk, const float* __restrict__ Wv,
    ushort* __restrict__ qb16, ushort* __restrict__ kb16, ushort* __restrict__ vb16, int ldx)
{
  int mode = blockIdx.y;
  const float* W = (mode==0)?Wq:(mode==1)?Wk:Wv;
  const ushort* X = Xall + mode*1024;
  int row = blockIdx.x;
  int b = row >> 10, t = row & 1023;
  int tid = threadIdx.x;
  int c0 = tid << 2;
  float w[4][4];
  #pragma unroll
  for (int c = 0; c < 4; ++c) {
    float4 wv = *(const float4*)&W[(c0 + c)*4];
    w[c][0]=wv.x; w[c][1]=wv.y; w[c][2]=wv.z; w[c][3]=wv.w;
  }
  float acc[4] = {0.f,0.f,0.f,0.f};
  #pragma unroll
  for (int j = 0; j < 4; ++j) {
    int tt = t - 3 + j;
    if (tt >= 0) {
      ushort4 xv = *(const ushort4*)&X[(size_t)(b*1024 + tt)*ldx + c0];
      acc[0] += w[0][j]*b2f(xv.x); acc[1] += w[1][j]*b2f(xv.y);
      acc[2] += w[2][j]*b2f(xv.z); acc[3] += w[3][j]*b2f(xv.w);
    }
  }
  #pragma unroll
  for (int c = 0; c < 4; ++c) acc[c] *= sigm(acc[c]);
  if (mode < 2) {
    float ss = acc[0]*acc[0]+acc[1]*acc[1]+acc[2]*acc[2]+acc[3]*acc[3];
    ss += __shfl_xor(ss, 1); ss += __shfl_xor(ss, 2); ss += __shfl_xor(ss, 4);
    ss += __shfl_xor(ss, 8); ss += __shfl_xor(ss, 16);
    float r = rsqrtf(ss + 1e-6f);
    if (mode == 0) r *= SCALE_Q;
    acc[0]*=r; acc[1]*=r; acc[2]*=r; acc[3]*=r;
  }
  size_t o = (size_t)(b*1024 + t)*1024 + c0;
  ushort* Y = (mode==0)?qb16:(mode==1)?kb16:vb16;
  ushort4 yb; yb.x=f2b(acc[0]); yb.y=f2b(acc[1]); yb.z=f2b(acc[2]); yb.w=f2b(acc[3]);
  *(ushort4*)&Y[o] = yb;
}

// -------- per-(b,h) log-decay cumsum, one block per bh --------
__global__ __launch_bounds__(256) void gc2(const float* __restrict__ xs,
    const float* __restrict__ A_log, const float* __restrict__ dt_bias,
    float* __restrict__ gc)
{
  int bh = blockIdx.x, b = bh >> 3, h = bh & 7;
  __shared__ float sc[256];
  int tid = threadIdx.x;
  float aexp = __expf(A_log[h]), db = dt_bias[h];
  int t0 = tid*4;
  float g[4], csum = 0.f;
  #pragma unroll
  for (int z = 0; z < 4; ++z) {
    float zv = xs[(size_t)(b*1024 + t0 + z)*104 + 8 + h] + db;
    float sp = (zv > 20.f) ? zv : log1pf(__expf(zv));
    csum += -aexp*sp;
    g[z] = csum;
  }
  sc[tid] = csum;
  __syncthreads();
  for (int ofs = 1; ofs < 256; ofs <<= 1) {
    float v = (tid >= ofs) ? sc[tid-ofs] : 0.f;
    __syncthreads();
    sc[tid] += v;
    __syncthreads();
  }
  float excl = sc[tid] - csum;
  #pragma unroll
  for (int z = 0; z < 4; ++z) gc[bh*1024 + t0 + z] = excl + g[z];
}

// -------- chunk prep v2: MFMA A-build (K already bf16 -> identical numerics) --------
// K tile in LDS as swizzled bf16 [64][128] (slot16B ^= row&15). A = tril(bl*e^dgc*KK^T)
// via 16x16x32 MFMA (wave w computes its <=w+1 sub-diagonal 16-blocks). Fwd-sub unchanged.
__global__ __launch_bounds__(256) void chunk_prep(const ushort* __restrict__ Kg16,
    const ushort* __restrict__ Vg16, const float* __restrict__ xs,
    const float* __restrict__ gcg, float* __restrict__ cw, ushort* __restrict__ cWk16,
    ushort* __restrict__ cKpT16, float* __restrict__ eD)
{
  int blk = blockIdx.x;
  int bh = blk >> 4, ck = blk & 15;
  int b = bh >> 3, h = bh & 7;
  int a = ck << 6;
  __shared__ ushort Kl[64*128];     // 16KB, swizzled
  __shared__ float As[64][68];
  __shared__ float gcl[65];
  __shared__ float bl[64];
  __shared__ float egc[64];
  __shared__ float edt[64];
  int tid = threadIdx.x;
  int wave = tid >> 6, lane = tid & 63;
  int l15 = lane & 15, kh = lane >> 4;
  // stage K tile (bf16, swizzled): 2048 ushort4 units, 8/thread
  for (int e = tid; e < 2048; e += 256) {
    int t = e >> 5;                     // 32 ushort4 per 128-ushort row
    int c4u = (e & 31) << 2;            // ushort index in row
    ushort4 kv = *(const ushort4*)&Kg16[(size_t)(b*1024 + a + t)*1024 + h*128 + c4u];
    unsigned slot = (unsigned)(c4u >> 3) ^ (unsigned)(t & 15);
    *(ushort4*)((char*)Kl + t*256 + slot*16 + (c4u & 7)*2) = kv;
  }
  if (tid < 64) {
    gcl[tid] = gcg[bh*1024 + a + tid];
    bl[tid] = sigm(xs[(size_t)(b*1024 + a + tid)*104 + h]);
  }
  if (tid == 64) gcl[64] = (ck < 15) ? gcg[bh*1024 + a + 64] : 0.f;
  __syncthreads();
  if (tid < 64) {
    egc[tid] = __expf(gcl[tid] - gcl[0]);
    edt[tid] = (ck < 15) ? __expf(gcl[64] - gcl[tid]) : 0.f;
  }
  // A-build: wave w covers t in [16w,16w+16); jt blocks 0..w (s<=t region)
  {
    int arow = wave*16 + l15;
    int asw = arow & 15;
    for (int jt = 0; jt <= wave; ++jt) {
      int brow = jt*16 + l15;
      int bsw = brow & 15;
      f32x4 acc = {0.f,0.f,0.f,0.f};
      #pragma unroll
      for (int ks = 0; ks < 4; ++ks) {
        bf16x8 afr = *(const bf16x8*)((char*)Kl + arow*256 + (((ks*4 + kh) ^ asw) << 4));
        bf16x8 bfr = *(const bf16x8*)((char*)Kl + brow*256 + (((ks*4 + kh) ^ bsw) << 4));
        acc = __builtin_amdgcn_mfma_f32_16x16x32_bf16(afr, bfr, acc, 0, 0, 0);
      }
      int s = jt*16 + l15;
      #pragma unroll
      for (int r = 0; r < 4; ++r) {
        int t = wave*16 + kh*4 + r;
        if (s < t) As[t][s] = bl[t]*acc[r]*__expf(gcl[t]-gcl[s]);
      }
    }
  }
  __syncthreads();
  int c = tid;
  float u[64];
  if (c < 128) {
    #pragma unroll
    for (int t = 0; t < 64; ++t)
      u[t] = bl[t]*b2f(Vg16[(size_t)(b*1024 + a + t)*1024 + h*128 + c]);
  } else {
    int d = c - 128;
    unsigned dslot = (unsigned)(d >> 3);
    #pragma unroll
    for (int t = 0; t < 64; ++t) {
      ushort kv = *(const ushort*)((char*)Kl + t*256 + ((dslot ^ (unsigned)(t & 15)) << 4) + (d & 7)*2);
      u[t] = bl[t]*egc[t]*b2f(kv);
    }
  }
  #pragma unroll
  for (int t = 1; t < 64; ++t) {
    float acc = u[t];
    int s = 0;
    #pragma unroll
    for (; s + 4 <= t; s += 4) {
      float4 a4 = *(float4*)&As[t][s];
      acc -= a4.x*u[s] + a4.y*u[s+1] + a4.z*u[s+2] + a4.w*u[s+3];
    }
    #pragma unroll
    for (; s < t; ++s) acc -= As[t][s]*u[s];
    u[t] = acc;
  }
  size_t cbase = (size_t)blk*8192;
  if (c < 128) {
    #pragma unroll
    for (int t = 0; t < 64; ++t)
      cw[cbase + t*128 + c] = u[t];
  } else {
    int d = c - 128;
    unsigned dslot = (unsigned)(d >> 3);
    #pragma unroll
    for (int t = 0; t < 64; ++t) {
      cWk16[cbase + t*128 + d] = f2b(-u[t]);
      ushort kv = *(const ushort*)((char*)Kl + t*256 + ((dslot ^ (unsigned)(t & 15)) << 4) + (d & 7)*2);
      cKpT16[cbase + d*64 + t] = f2b(b2f(kv)*edt[t]);
    }
  }
  if (tid == 0) eD[blk] = (ck < 15) ? __expf(gcl[64]-gcl[0]) : 0.f;
}

// -------- chunk scan v6: MFMA both phases. 256 blocks = 16 e-slices(8) x 16 bh --------
__global__ __launch_bounds__(256) void chunk_scan6(const float* __restrict__ cw,
    const ushort* __restrict__ cWk16, const ushort* __restrict__ cKpT16,
    const float* __restrict__ eD, ushort* __restrict__ Ut)
{
  int blk = blockIdx.x;
  int slice = blk >> 4, bh = blk & 15;
  int e_base = slice << 3;
  __shared__ ushort Wks[2][8192];
  __shared__ ushort Kps[2][8192];
  __shared__ ushort StT[16*128];
  __shared__ ushort usT[16*64];
  __shared__ float  Stf[128*16];
  int tid = threadIdx.x;
  int wave = tid >> 6, lane = tid & 63;
  int l15 = lane & 15, kh = lane >> 4;
  for (int idx = tid; idx < 16*128; idx += 256) StT[idx] = 0;
  for (int idx = tid; idx < 16*64; idx += 256) usT[idx] = 0;
  for (int idx = tid; idx < 128*16; idx += 256) Stf[idx] = 0.f;

  int e = l15;
  int t0 = wave*16 + kh*4;
  int ci0 = bh << 4;
  f32x4 wcur = {0.f,0.f,0.f,0.f};
  if (e < 8) {
    #pragma unroll
    for (int r = 0; r < 4; ++r)
      wcur[r] = cw[(size_t)ci0*8192 + (t0+r)*128 + e_base + e];
  }
  {
    const char* wg = (const char*)(cWk16 + (size_t)ci0*8192);
    const char* kg = (const char*)(cKpT16 + (size_t)ci0*8192);
    #pragma unroll
    for (int j = 0; j < 4; ++j) {
      unsigned off = (j<<12) + (tid<<4);
      unsigned wrow = off >> 8, wslot = (off >> 4) & 15;
      unsigned wsrc = wrow*256 + ((wslot ^ (wrow & 15)) << 4);
      __builtin_amdgcn_global_load_lds((const __attribute__((address_space(1))) unsigned*)(wg + wsrc),
        (__attribute__((address_space(3))) unsigned*)((char*)&Wks[0][0] + off), 16, 0, 0);
      unsigned krow = off >> 7, kslot = (off >> 4) & 7;
      unsigned ksrc = krow*128 + ((kslot ^ (krow & 7)) << 4);
      __builtin_amdgcn_global_load_lds((const __attribute__((address_space(1))) unsigned*)(kg + ksrc),
        (__attribute__((address_space(3))) unsigned*)((char*)&Kps[0][0] + off), 16, 0, 0);
    }
  }
  __syncthreads();

  for (int i = 0; i < 16; ++i) {
    int ci = ci0 + i, a = i << 6, cur = i & 1;
    f32x4 wnext = {0.f,0.f,0.f,0.f};
    if (i < 15) {
      if (e < 8) {
        #pragma unroll
        for (int r = 0; r < 4; ++r)
          wnext[r] = cw[(size_t)(ci+1)*8192 + (t0+r)*128 + e_base + e];
      }
      const char* wg = (const char*)(cWk16 + (size_t)(ci+1)*8192);
      const char* kg = (const char*)(cKpT16 + (size_t)(ci+1)*8192);
      char* wl = (char*)&Wks[cur^1][0];
      char* kl = (char*)&Kps[cur^1][0];
      #pragma unroll
      for (int j = 0; j < 4; ++j) {
        unsigned off = (j<<12) + (tid<<4);
        unsigned wrow = off >> 8, wslot = (off >> 4) & 15;
        unsigned wsrc = wrow*256 + ((wslot ^ (wrow & 15)) << 4);
        __builtin_amdgcn_global_load_lds((const __attribute__((address_space(1))) unsigned*)(wg + wsrc),
          (__attribute__((address_space(3))) unsigned*)(wl + off), 16, 0, 0);
        unsigned krow = off >> 7, kslot = (off >> 4) & 7;
        unsigned ksrc = krow*128 + ((kslot ^ (krow & 7)) << 4);
        __builtin_amdgcn_global_load_lds((const __attribute__((address_space(1))) unsigned*)(kg + ksrc),
          (__attribute__((address_space(3))) unsigned*)(kl + off), 16, 0, 0);
      }
    }
    {
      f32x4 d = wcur;
      const char* wkb = (const char*)&Wks[cur][0];
      int arow = wave*16 + l15;
      #pragma unroll
      for (int ks = 0; ks < 4; ++ks) {
        bf16x8 afr = *(const bf16x8*)(wkb + arow*256 + (((ks*4 + kh) ^ l15) << 4));
        bf16x8 bfr = *(const bf16x8*)((const char*)StT + l15*256 + (((ks*4 + kh) ^ l15) << 4));
        d = __builtin_amdgcn_mfma_f32_16x16x32_bf16(afr, bfr, d, 0, 0, 0);
      }
      if (e < 8) {
        ushort4 uw;
        uw.x = f2b(d[0]); uw.y = f2b(d[1]); uw.z = f2b(d[2]); uw.w = f2b(d[3]);
        *(ushort4*)((char*)usT + e*128 + (((t0>>3) ^ (e&7)) << 4) + (t0&7)*2) = uw;
        *(ushort4*)&Ut[(size_t)(bh*128 + e_base + e)*1024 + a + t0] = uw;
      }
    }
    asm volatile("s_waitcnt lgkmcnt(0)" ::: "memory");
    __builtin_amdgcn_s_barrier();
    __builtin_amdgcn_sched_barrier(0);
    if (i < 15) {
      float ed = eD[ci];
      const char* kpb = (const char*)&Kps[cur][0];
      #pragma unroll
      for (int mt = 0; mt < 2; ++mt) {
        int krow = (wave*2 + mt)*16 + l15;
        int k0 = (wave*2 + mt)*16 + kh*4;
        f32x4 c;
        #pragma unroll
        for (int r = 0; r < 4; ++r) c[r] = ed * Stf[(k0+r)*16 + e];
        #pragma unroll
        for (int ts = 0; ts < 2; ++ts) {
          bf16x8 afr = *(const bf16x8*)(kpb + krow*128 + (((ts*4 + kh) ^ (krow&7)) << 4));
          bf16x8 bfr = *(const bf16x8*)((const char*)usT + l15*128 + (((ts*4 + kh) ^ (l15&7)) << 4));
          c = __builtin_amdgcn_mfma_f32_16x16x32_bf16(afr, bfr, c, 0, 0, 0);
        }
        #pragma unroll
        for (int r = 0; r < 4; ++r) Stf[(k0+r)*16 + e] = c[r];
        if (e < 8) {
          ushort4 sw;
          sw.x = f2b(c[0]); sw.y = f2b(c[1]); sw.z = f2b(c[2]); sw.w = f2b(c[3]);
          *(ushort4*)((char*)StT + e*256 + (((k0>>3) ^ e) << 4) + (k0&7)*2) = sw;
        }
      }
      wcur = wnext;
      asm volatile("s_waitcnt vmcnt(0) lgkmcnt(0)" ::: "memory");
      __builtin_amdgcn_s_barrier();
      __builtin_amdgcn_sched_barrier(0);
    }
  }
}

// -------- MFMA log-linear readout v3: LDS-staged K/Ut, double-buffered --------
__global__ __launch_bounds__(256) void readout3(const ushort* __restrict__ Qb,
    const ushort* __restrict__ Kb, const ushort* __restrict__ Ut,
    const float* __restrict__ gcg, const float* __restrict__ xs,
    float* __restrict__ Og)
{
  int blk = blockIdx.x;
  int bh = blk >> 4, ic = blk & 15;
  int half = blockIdx.y;
  int b = bh >> 3, h = bh & 7;
  int tbase = ic << 6;
  __shared__ ushort Ks[2][8192];
  __shared__ ushort Us[2][8192];
  __shared__ ushort Pl[4][1024];
  __shared__ float lamS[64][12];
  int tid = threadIdx.x;
  int wave = tid >> 6, lane = tid & 63;
  int l15 = lane & 15, kh = lane >> 4;

  const char* kgb = (const char*)Kb + ((size_t)(b*1024)*1024 + h*128)*2;
  const char* ugb = (const char*)Ut + ((size_t)(bh*128)*1024)*2;

  for (int e = tid; e < 64*11; e += 256) {
    int t = e/11, l = e%11;
    lamS[t][l] = sigm(xs[(size_t)(b*1024+tbase+t)*104 + 16 + h*11 + l]);
  }
  int tl = kh*4;
  float gct_r[4];
  #pragma unroll
  for (int r = 0; r < 4; ++r) gct_r[r] = gcg[bh*1024 + tbase + wave*16 + tl + r];
  bf16x8 qf[4];
  {
    const ushort* qp = &Qb[(size_t)(b*1024 + tbase + wave*16 + l15)*1024 + h*128 + kh*8];
    #pragma unroll
    for (int kk = 0; kk < 4; ++kk) qf[kk] = *(const bf16x8*)(qp + kk*32);
  }

  f32x4 accO[8] = {};
  int nsteps = ic + 1;
  int jmid = (nsteps + 1) >> 1;
  int j0 = half ? jmid : 0;
  int j1 = half ? nsteps : jmid;
  ushort* Pw = &Pl[wave][0];

  if (j0 < j1) {
    {
      const char* kg = kgb + (size_t)(j0<<6)*2048;
      const char* ug = ugb + (size_t)(j0<<6)*2;
      #pragma unroll
      for (int it = 0; it < 4; ++it) {
        unsigned off = (it<<12) + (tid<<4);
        unsigned krow = off >> 8, kc = (off >> 4) & 15;
        unsigned ksrc = krow*2048 + ((kc ^ (krow & 15)) << 4);
        __builtin_amdgcn_global_load_lds((const __attribute__((address_space(1))) unsigned*)(kg + ksrc),
          (__attribute__((address_space(3))) unsigned*)((char*)&Ks[0][0] + off), 16, 0, 0);
        unsigned ud = off >> 7, uc = (off >> 4) & 7;
        unsigned usrc = ud*2048 + ((uc ^ (ud & 7)) << 4);
        __builtin_amdgcn_global_load_lds((const __attribute__((address_space(1))) unsigned*)(ug + usrc),
          (__attribute__((address_space(3))) unsigned*)((char*)&Us[0][0] + off), 16, 0, 0);
      }
    }
    __syncthreads();
    int cur = 0;
    for (int j = j0; j < j1; ++j) {
      int sbase = j << 6;
      if (j + 1 < j1) {
        const char* kg = kgb + (size_t)((j+1)<<6)*2048;
        const char* ug = ugb + (size_t)((j+1)<<6)*2;
        char* kl = (char*)&Ks[cur^1][0];
        char* ul = (char*)&Us[cur^1][0];
        #pragma unroll
        for (int it = 0; it < 4; ++it) {
          unsigned off = (it<<12) + (tid<<4);
          unsigned krow = off >> 8, kc = (off >> 4) & 15;
          unsigned ksrc = krow*2048 + ((kc ^ (krow & 15)) << 4);
          __builtin_amdgcn_global_load_lds((const __attribute__((address_space(1))) unsigned*)(kg + ksrc),
            (__attribute__((address_space(3))) unsigned*)(kl + off), 16, 0, 0);
          unsigned ud = off >> 7, uc = (off >> 4) & 7;
          unsigned usrc = ud*2048 + ((uc ^ (ud & 7)) << 4);
          __builtin_amdgcn_global_load_lds((const __attribute__((address_space(1))) unsigned*)(ug + usrc),
            (__attribute__((address_space(3))) unsigned*)(ul + off), 16, 0, 0);
        }
      }
      float gcs_r[4];
      #pragma unroll
      for (int jt = 0; jt < 4; ++jt)
        gcs_r[jt] = gcg[bh*1024 + sbase + jt*16 + l15];
      f32x4 accS[4] = {};
      const char* ksb = (const char*)&Ks[cur][0];
      #pragma unroll
      for (int jt = 0; jt < 4; ++jt) {
        int row = jt*16 + l15;
        int rsw = row & 15;
        #pragma unroll
        for (int kk = 0; kk < 4; ++kk) {
          bf16x8 kf = *(const bf16x8*)(ksb + row*256 + (((kk*4 + kh) ^ rsw) << 4));
          accS[jt] = __builtin_amdgcn_mfma_f32_16x16x32_bf16(qf[kk], kf, accS[jt], 0, 0, 0);
        }
      }
      #pragma unroll
      for (int jt = 0; jt < 4; ++jt) {
        int sg = sbase + jt*16 + l15;
        #pragma unroll
        for (int r = 0; r < 4; ++r) {
          int t_loc = tl + r;
          int tg = tbase + wave*16 + t_loc;
          float pv = 0.f;
          if (sg <= tg) {
            int lev = 31 - __clz((unsigned)((tg+1) ^ sg));
            lev = lev > 10 ? 10 : lev;
            pv = accS[jt][r] * __expf(gct_r[r] - gcs_r[jt]) * lamS[wave*16 + t_loc][lev];
          }
          int bo = (t_loc << 7) + ((jt*16 + l15) << 1);
          bo ^= (t_loc & 7) << 4;
          *(ushort*)((char*)Pw + bo) = f2b(pv);
        }
      }
      const char* usb = (const char*)&Us[cur][0];
      #pragma unroll
      for (int ks = 0; ks < 2; ++ks) {
        int bo = (l15 << 7) + ((ks*32 + kh*8) << 1);
        bo ^= (l15 & 7) << 4;
        bf16x8 pa = *(bf16x8*)((char*)Pw + bo);
        #pragma unroll
        for (int dt = 0; dt < 8; ++dt) {
          int d = dt*16 + l15;
          bf16x8 uf = *(const bf16x8*)(usb + d*128 + (((ks*4 + kh) ^ (d & 7)) << 4));
          accO[dt] = __builtin_amdgcn_mfma_f32_16x16x32_bf16(pa, uf, accO[dt], 0, 0, 0);
        }
      }
      __syncthreads();
      cur ^= 1;
    }
  }
  float* og = Og + (size_t)half*2097152;
  #pragma unroll
  for (int dt = 0; dt < 8; ++dt) {
    #pragma unroll
    for (int r = 0; r < 4; ++r) {
      int row = tbase + wave*16 + tl + r;
      og[(size_t)(b*1024 + row)*1024 + h*128 + dt*16 + l15] = accO[dt][r];
    }
  }
}

// -------- gated RMSNorm (sums two partial O buffers) -> bf16 --------
__global__ __launch_bounds__(64) void normgate(const float* __restrict__ O1,
    const float* __restrict__ O2, const float* __restrict__ G,
    const float* __restrict__ norm_w, ushort* __restrict__ Y)
{
  int row = blockIdx.x;
  int lane = threadIdx.x;
  size_t base = (size_t)(row >> 3)*1024 + (size_t)(row & 7)*128;
  float2 oa = *(const float2*)&O1[base + lane*2];
  float2 ob = *(const float2*)&O2[base + lane*2];
  float ox = oa.x + ob.x, oy = oa.y + ob.y;
  float ss = ox*ox + oy*oy;
  #pragma unroll
  for (int m = 1; m < 64; m <<= 1) ss += __shfl_xor(ss, m);
  float r = rsqrtf(ss * (1.f/128.f) + 1e-5f);
  float2 g = *(const float2*)&G[base + lane*2];
  ushort2 y;
  y.x = f2b(ox * r * norm_w[lane*2+0] * (g.x * sigm(g.x)));
  y.y = f2b(oy * r * norm_w[lane*2+1] * (g.y * sigm(g.y)));
  *(ushort2*)&Y[base + lane*2] = y;
}

extern "C" void kernel_launch(void* const* d_in, const int* in_sizes, int n_in,
                              void* d_out, int out_size, void* d_ws, size_t ws_size,
                              hipStream_t stream)
{
  const float* x    = (const float*)d_in[0];
  const float* Wq   = (const float*)d_in[3];
  const float* Wk   = (const float*)d_in[4];
  const float* Wv   = (const float*)d_in[5];
  const float* Wb   = (const float*)d_in[6];
  const float* Wa   = (const float*)d_in[7];
  const float* Wl   = (const float*)d_in[8];
  const float* Wg   = (const float*)d_in[9];
  const float* Wo   = (const float*)d_in[10];
  const float* cq   = (const float*)d_in[11];
  const float* ck   = (const float*)d_in[12];
  const float* cv   = (const float*)d_in[13];
  const float* A_log   = (const float*)d_in[14];
  const float* dt_bias = (const float*)d_in[15];
  const float* norm_w  = (const float*)d_in[16];
  float* out = (float*)d_out;

  float* p = (float*)d_ws;
  float* xqkv = p;  p += 6291456;            // region reused: qkv bf16 then cw/cWk16/cKpT16
  float* xg   = p;  p += 2097152;
  float* kbu  = p;  p += 2097152;            // (spare)
  float* vbu  = p;  p += 2097152;            // vb16 lives here
  float* o1   = p;  p += 2097152;            // o1,o2 MUST be adjacent (readout3 half offset)
  float* o2   = p;  p += 2097152;
  float* xs   = p;  p += 212992;
  float* gc   = p;  p += 16384;
  float* eD   = p;  p += 256;
  ushort* x16 = (ushort*)p; p += 1048576;    // [2048][1024] bf16
  ushort* Wt4 = (ushort*)p; p += 2097152;    // [4096][1024] bf16
  ushort* Wot = (ushort*)p; p += 524288;     // [1024][1024] bf16
  float* Wsm  = p;  p += 106496;
  ushort* yb16= (ushort*)p; p += 1048576;    // [2048][1024] bf16
  ushort* qb16= (ushort*)p; p += 1048576;    // [2048][1024] bf16
  ushort* kb16= (ushort*)p; p += 1048576;    // [2048][1024] bf16
  ushort* ut16= (ushort*)p; p += 1048576;    // [16*128][1024] bf16
  ushort* xqkv16 = (ushort*)xqkv;            // [2048][3072] bf16 (12MB)
  ushort* vb16 = (ushort*)vbu;               // [2048][1024] bf16
  float* cw  = xqkv;                          // overlays after convs
  ushort* cWk16  = (ushort*)(xqkv + 2097152);
  ushort* cKpT16 = (ushort*)(xqkv + 3145728);
  float* part = o1;                           // [8][2048][104] partials; o1 dead until readout3
  (void)kbu;

  dim3 blk(256);
  prep_all<<<dim3(32,32,8), blk, 0, stream>>>(Wq, Wk, Wv, Wg, Wo, x, Wb, Wa, Wl,
                                              Wt4, Wot, x16, Wsm);
  gemm_bf16<<<dim3(32,16), blk, 0, stream>>>(x16, Wt4, xqkv16, xg, 2048, 4096, 1024,
                                             3072, 3072, 1024, 1);
  skinny104<<<dim3(32,8), blk, 0, stream>>>(x, Wsm, part);
  reduce8<<<dim3(833), blk, 0, stream>>>(part, xs);
  conv_fused<<<dim3(2048,3), blk, 0, stream>>>(xqkv16, cq, ck, cv, qb16, kb16, vb16, 3072);
  gc2<<<dim3(16), blk, 0, stream>>>(xs, A_log, dt_bias, gc);
  chunk_prep<<<dim3(256), blk, 0, stream>>>(kb16, vb16, xs, gc, cw, cWk16, cKpT16, eD);
  chunk_scan6<<<dim3(256), blk, 0, stream>>>(cw, cWk16, cKpT16, eD, ut16);
  readout3<<<dim3(256,2), blk, 0, stream>>>(qb16, kb16, ut16, gc, xs, o1);
  normgate<<<dim3(16384), dim3(64), 0, stream>>>(o1, o2, xg, norm_w, yb16);
  gemm_bf16<<<dim3(8,16), blk, 0, stream>>>(yb16, Wot, out, out, 2048, 1024, 1024,
                                            1024, 1024, 1024, 0);
}

// Round 18
// 189.658 us; speedup vs baseline: 2.3637x; 1.0178x over previous
//
#include <hip/hip_runtime.h>
#include <hip/hip_bf16.h>
#include <math.h>

// B=2, T=1024, D=1024, H=8, Dh=128, L=11, conv=4; chunk C=64, 16 chunks/bh
#define SCALE_Q 0.08838834764831845f

typedef __bf16 bf16x8 __attribute__((ext_vector_type(8)));
typedef float f32x4 __attribute__((ext_vector_type(4)));

static __device__ __forceinline__ float sigm(float x){ return 1.f/(1.f+__expf(-x)); }
static __device__ __forceinline__ ushort f2b(float v){
  __hip_bfloat16 t = __float2bfloat16(v);
  return __builtin_bit_cast(ushort, t);
}
static __device__ __forceinline__ float b2f(ushort u){
  unsigned v = (unsigned)u << 16; return __builtin_bit_cast(float, v);
}

// ---------------- fused prep: z=0..4 transcast 5 weights; z=5,6 cast x; z=7 Wsm ----------------
__global__ __launch_bounds__(256) void prep_all(const float* __restrict__ Wq,
    const float* __restrict__ Wk, const float* __restrict__ Wv,
    const float* __restrict__ Wg, const float* __restrict__ Wo,
    const float* __restrict__ X, const float* __restrict__ Wb,
    const float* __restrict__ Wa, const float* __restrict__ Wl,
    ushort* __restrict__ Wt4, ushort* __restrict__ Wot,
    ushort* __restrict__ x16, float* __restrict__ Wsm)
{
  int z = blockIdx.z;
  int tid = threadIdx.x;
  int flat = blockIdx.y * 32 + blockIdx.x;
  if (z < 5) {
    __shared__ float tile[32][36];
    const float* W = (z==0)?Wq:(z==1)?Wk:(z==2)?Wv:(z==3)?Wg:Wo;
    ushort* Wt = (z<4)? (Wt4 + (size_t)z*1048576) : Wot;
    int n0 = blockIdx.x*32, k0 = blockIdx.y*32;
    int r = tid >> 3, c4 = (tid & 7) << 2;
    *(float4*)&tile[r][c4] = *(const float4*)&W[(size_t)(k0 + r)*1024 + n0 + c4];
    __syncthreads();
    ushort4 o;
    o.x = f2b(tile[c4+0][r]); o.y = f2b(tile[c4+1][r]);
    o.z = f2b(tile[c4+2][r]); o.w = f2b(tile[c4+3][r]);
    *(ushort4*)&Wt[(size_t)(n0 + r)*1024 + k0 + c4] = o;
  } else if (z < 7) {
    int idx = (z-5)*262144 + flat*256 + tid;
    float4 v = *(const float4*)&X[(size_t)idx*4];
    ushort4 o; o.x=f2b(v.x); o.y=f2b(v.y); o.z=f2b(v.z); o.w=f2b(v.w);
    *(ushort4*)&x16[(size_t)idx*4] = o;
  } else {
    int idx = flat*256 + tid;
    if (idx < 1024*104) {
      int k = idx / 104, c = idx % 104;
      float v = (c < 8) ? Wb[k*8+c] : (c < 16) ? Wa[k*8+(c-8)] : Wl[k*88+(c-16)];
      Wsm[idx] = v;
    }
  }
}

// ---------------- bf16 MFMA GEMM, 3-stage prefetch, counted vmcnt, XCD swizzle ----------------
// C0 bf16/f32 per flag; C1 bf16 if c1bf16 else f32.
__global__ __launch_bounds__(256) void gemm_bf16(const ushort* __restrict__ A,
    const ushort* __restrict__ Bt, void* __restrict__ C0, void* __restrict__ C1,
    int M, int N, int K, int nsplit, int ld0, int ld1, int c0bf16, int c1bf16)
{
  __shared__ ushort As[3][128*32];
  __shared__ ushort Bs[3][128*32];
  int tid = threadIdx.x;
  int gx = gridDim.x;
  int nwg = gx * gridDim.y;
  int id = blockIdx.y * gx + blockIdx.x;
  int id2 = (id & 7) * (nwg >> 3) + (id >> 3);
  int bm = (id2 / gx) * 128, bn = (id2 % gx) * 128;
  int wave = tid >> 6, lane = tid & 63;
  int wm = (wave >> 1) * 64, wn = (wave & 1) * 64;
  int l16 = lane & 15, kh = lane >> 4;
  f32x4 acc[4][4] = {};
  int rowA0 = tid >> 2, boA = (tid & 3) * 16;
  int niter = K >> 5;

  #pragma unroll
  for (int s = 0; s < 2; ++s) {
    int k0 = s << 5;
    #pragma unroll
    for (int j = 0; j < 2; ++j) {
      int row = rowA0 + j*64;
      const char* gA = (const char*)A + (((size_t)(bm+row)*K + k0)*2 + boA);
      const char* gB = (const char*)Bt + (((size_t)(bn+row)*K + k0)*2 + boA);
      __builtin_amdgcn_global_load_lds((const __attribute__((address_space(1))) unsigned*)gA,
        (__attribute__((address_space(3))) unsigned*)((char*)&As[s][0] + row*64 + boA), 16, 0, 0);
      __builtin_amdgcn_global_load_lds((const __attribute__((address_space(1))) unsigned*)gB,
        (__attribute__((address_space(3))) unsigned*)((char*)&Bs[s][0] + row*64 + boA), 16, 0, 0);
    }
  }
  asm volatile("s_waitcnt vmcnt(4)" ::: "memory");
  __builtin_amdgcn_s_barrier();
  __builtin_amdgcn_sched_barrier(0);
  for (int i = 0; i < niter; ++i) {
    int cur = i % 3;
    if (i + 2 < niter) {
      int k0 = (i+2) << 5;
      int nb = (i+2) % 3;
      char* al = (char*)&As[nb][0];
      char* bl = (char*)&Bs[nb][0];
      #pragma unroll
      for (int j = 0; j < 2; ++j) {
        int row = rowA0 + j*64;
        const char* gA = (const char*)A + (((size_t)(bm+row)*K + k0)*2 + boA);
        const char* gB = (const char*)Bt + (((size_t)(bn+row)*K + k0)*2 + boA);
        __builtin_amdgcn_global_load_lds((const __attribute__((address_space(1))) unsigned*)gA,
          (__attribute__((address_space(3))) unsigned*)(al + row*64 + boA), 16, 0, 0);
        __builtin_amdgcn_global_load_lds((const __attribute__((address_space(1))) unsigned*)gB,
          (__attribute__((address_space(3))) unsigned*)(bl + row*64 + boA), 16, 0, 0);
      }
    }
    bf16x8 af[4], bfr[4];
    #pragma unroll
    for (int ii = 0; ii < 4; ++ii)
      af[ii] = *(bf16x8*)((char*)&As[cur][0] + (wm + ii*16 + l16)*64 + kh*16);
    #pragma unroll
    for (int j = 0; j < 4; ++j)
      bfr[j] = *(bf16x8*)((char*)&Bs[cur][0] + (wn + j*16 + l16)*64 + kh*16);
    #pragma unroll
    for (int ii = 0; ii < 4; ++ii)
      #pragma unroll
      for (int j = 0; j < 4; ++j)
        acc[ii][j] = __builtin_amdgcn_mfma_f32_16x16x32_bf16(af[ii], bfr[j], acc[ii][j], 0, 0, 0);
    if (i + 1 < niter) {
      if (i + 2 < niter) {
        asm volatile("s_waitcnt vmcnt(4) lgkmcnt(0)" ::: "memory");
      } else {
        asm volatile("s_waitcnt vmcnt(0) lgkmcnt(0)" ::: "memory");
      }
      __builtin_amdgcn_s_barrier();
      __builtin_amdgcn_sched_barrier(0);
    }
  }
  int rg = lane >> 4;
  #pragma unroll
  for (int i = 0; i < 4; ++i) {
    #pragma unroll
    for (int j = 0; j < 4; ++j) {
      int col = bn + wn + j*16 + l16;
      #pragma unroll
      for (int r = 0; r < 4; ++r) {
        int row = bm + wm + i*16 + rg*4 + r;
        float v = acc[i][j][r];
        if (col < nsplit) {
          if (c0bf16) ((ushort*)C0)[(size_t)row*ld0 + col] = f2b(v);
          else        ((float*)C0)[(size_t)row*ld0 + col] = v;
        } else {
          if (c1bf16) ((ushort*)C1)[(size_t)row*ld1 + (col - nsplit)] = f2b(v);
          else        ((float*)C1)[(size_t)row*ld1 + (col - nsplit)] = v;
        }
      }
    }
  }
}

// ---------------- Wo GEMM: 64x128 tile, 2 waves/block (128 thr), f32 out ----------------
__global__ __launch_bounds__(128) void gemm_wo64(const ushort* __restrict__ A,
    const ushort* __restrict__ Bt, float* __restrict__ C, int K)
{
  __shared__ ushort As[3][64*32];
  __shared__ ushort Bs[3][128*32];
  int tid = threadIdx.x;
  int gx = gridDim.x;                       // 8 (N tiles)
  int nwg = gx * gridDim.y;                 // 256
  int id = blockIdx.y * gx + blockIdx.x;
  int id2 = (id & 7) * (nwg >> 3) + (id >> 3);
  int bm = (id2 / gx) * 64, bn = (id2 % gx) * 128;
  int wave = tid >> 6, lane = tid & 63;
  int wn = wave * 64;
  int l16 = lane & 15, kh = lane >> 4;
  f32x4 acc[4][4] = {};
  int rowA0 = tid >> 2, boA = (tid & 3) * 16;   // rows 0..31
  int niter = K >> 5;

  #pragma unroll
  for (int s = 0; s < 2; ++s) {
    int k0 = s << 5;
    #pragma unroll
    for (int j = 0; j < 2; ++j) {              // A: 64 rows
      int row = rowA0 + j*32;
      const char* gA = (const char*)A + (((size_t)(bm+row)*K + k0)*2 + boA);
      __builtin_amdgcn_global_load_lds((const __attribute__((address_space(1))) unsigned*)gA,
        (__attribute__((address_space(3))) unsigned*)((char*)&As[s][0] + row*64 + boA), 16, 0, 0);
    }
    #pragma unroll
    for (int j = 0; j < 4; ++j) {              // B: 128 rows
      int row = rowA0 + j*32;
      const char* gB = (const char*)Bt + (((size_t)(bn+row)*K + k0)*2 + boA);
      __builtin_amdgcn_global_load_lds((const __attribute__((address_space(1))) unsigned*)gB,
        (__attribute__((address_space(3))) unsigned*)((char*)&Bs[s][0] + row*64 + boA), 16, 0, 0);
    }
  }
  asm volatile("s_waitcnt vmcnt(6)" ::: "memory");   // stage0 (6 insts) landed
  __builtin_amdgcn_s_barrier();
  __builtin_amdgcn_sched_barrier(0);
  for (int i = 0; i < niter; ++i) {
    int cur = i % 3;
    if (i + 2 < niter) {
      int k0 = (i+2) << 5;
      int nb = (i+2) % 3;
      char* al = (char*)&As[nb][0];
      char* bl = (char*)&Bs[nb][0];
      #pragma unroll
      for (int j = 0; j < 2; ++j) {
        int row = rowA0 + j*32;
        const char* gA = (const char*)A + (((size_t)(bm+row)*K + k0)*2 + boA);
        __builtin_amdgcn_global_load_lds((const __attribute__((address_space(1))) unsigned*)gA,
          (__attribute__((address_space(3))) unsigned*)(al + row*64 + boA), 16, 0, 0);
      }
      #pragma unroll
      for (int j = 0; j < 4; ++j) {
        int row = rowA0 + j*32;
        const char* gB = (const char*)Bt + (((size_t)(bn+row)*K + k0)*2 + boA);
        __builtin_amdgcn_global_load_lds((const __attribute__((address_space(1))) unsigned*)(gB),
          (__attribute__((address_space(3))) unsigned*)(bl + row*64 + boA), 16, 0, 0);
      }
    }
    bf16x8 af[4], bfr[4];
    #pragma unroll
    for (int ii = 0; ii < 4; ++ii)
      af[ii] = *(bf16x8*)((char*)&As[cur][0] + (ii*16 + l16)*64 + kh*16);
    #pragma unroll
    for (int j = 0; j < 4; ++j)
      bfr[j] = *(bf16x8*)((char*)&Bs[cur][0] + (wn + j*16 + l16)*64 + kh*16);
    #pragma unroll
    for (int ii = 0; ii < 4; ++ii)
      #pragma unroll
      for (int j = 0; j < 4; ++j)
        acc[ii][j] = __builtin_amdgcn_mfma_f32_16x16x32_bf16(af[ii], bfr[j], acc[ii][j], 0, 0, 0);
    if (i + 1 < niter) {
      if (i + 2 < niter) {
        asm volatile("s_waitcnt vmcnt(6) lgkmcnt(0)" ::: "memory");
      } else {
        asm volatile("s_waitcnt vmcnt(0) lgkmcnt(0)" ::: "memory");
      }
      __builtin_amdgcn_s_barrier();
      __builtin_amdgcn_sched_barrier(0);
    }
  }
  int rg = lane >> 4;
  #pragma unroll
  for (int i = 0; i < 4; ++i) {
    #pragma unroll
    for (int j = 0; j < 4; ++j) {
      int col = bn + wn + j*16 + l16;
      #pragma unroll
      for (int r = 0; r < 4; ++r) {
        int row = bm + i*16 + rg*4 + r;
        C[(size_t)row*1024 + col] = acc[i][j][r];
      }
    }
  }
}

// -------- skinny split-K GEMM: part[ks][M][104] = x[M,k0:k0+128] @ Wsm[k0:k0+128][104] --------
__global__ __launch_bounds__(256) void skinny104(const float* __restrict__ X,
    const float* __restrict__ Wsm, float* __restrict__ part)
{
  __shared__ float XL[64][132];
  __shared__ float WsL[128][112];
  int tid = threadIdx.x;
  int m0 = blockIdx.x << 6;
  int k0 = blockIdx.y << 7;
  #pragma unroll
  for (int j = 0; j < 8; ++j) {
    int s = tid + j*256;
    int row = s >> 5, c4 = (s & 31) << 2;
    *(float4*)&XL[row][c4] = *(const float4*)&X[(size_t)(m0 + row)*1024 + k0 + c4];
  }
  {
    int k = tid >> 1, c = 104 + ((tid & 1) << 2);
    *(float4*)&WsL[k][c] = (float4){0.f,0.f,0.f,0.f};
  }
  {
    int k = tid >> 1, cb = (tid & 1) * 52;
    #pragma unroll
    for (int j = 0; j < 13; ++j) {
      *(float4*)&WsL[k][cb + j*4] = *(const float4*)&Wsm[(size_t)(k0 + k)*104 + cb + j*4];
    }
  }
  __syncthreads();
  int row = tid >> 2, cq = tid & 3;
  int cbase = cq * 28;
  f32x4 acc[7] = {};
  const float* xrow = &XL[row][0];
  #pragma unroll 4
  for (int k = 0; k < 128; ++k) {
    float xv = xrow[k];
    const f32x4* wr = (const f32x4*)&WsL[k][cbase];
    #pragma unroll
    for (int j = 0; j < 7; ++j) acc[j] += xv * wr[j];
  }
  float* pr = &part[((size_t)blockIdx.y*2048 + m0 + row)*104 + cbase];
  int nst = (cq == 3) ? 5 : 7;
  for (int j = 0; j < nst; ++j) *(f32x4*)&pr[j*4] = acc[j];
}

// -------- reduce 8 K-slice partials -> xs[2048][104] --------
__global__ __launch_bounds__(256) void reduce8(const float* __restrict__ part,
    float* __restrict__ xs)
{
  int idx = blockIdx.x*256 + threadIdx.x;
  if (idx >= 212992) return;
  float s = 0.f;
  #pragma unroll
  for (int i = 0; i < 8; ++i) s += part[(size_t)i*212992 + idx];
  xs[idx] = s;
}

// -------- fused depthwise causal conv(4)+silu q/k/v, all-bf16 outputs --------
__global__ __launch_bounds__(256) void conv_fused(const ushort* __restrict__ Xall,
    const float* __restrict__ Wq, const float* __restrict__ Wk, const float* __restrict__ Wv,
    ushort* __restrict__ qb16, ushort* __restrict__ kb16, ushort* __restrict__ vb16, int ldx)
{
  int mode = blockIdx.y;
  const float* W = (mode==0)?Wq:(mode==1)?Wk:Wv;
  const ushort* X = Xall + mode*1024;
  int row = blockIdx.x;
  int b = row >> 10, t = row & 1023;
  int tid = threadIdx.x;
  int c0 = tid << 2;
  float w[4][4];
  #pragma unroll
  for (int c = 0; c < 4; ++c) {
    float4 wv = *(const float4*)&W[(c0 + c)*4];
    w[c][0]=wv.x; w[c][1]=wv.y; w[c][2]=wv.z; w[c][3]=wv.w;
  }
  float acc[4] = {0.f,0.f,0.f,0.f};
  #pragma unroll
  for (int j = 0; j < 4; ++j) {
    int tt = t - 3 + j;
    if (tt >= 0) {
      ushort4 xv = *(const ushort4*)&X[(size_t)(b*1024 + tt)*ldx + c0];
      acc[0] += w[0][j]*b2f(xv.x); acc[1] += w[1][j]*b2f(xv.y);
      acc[2] += w[2][j]*b2f(xv.z); acc[3] += w[3][j]*b2f(xv.w);
    }
  }
  #pragma unroll
  for (int c = 0; c < 4; ++c) acc[c] *= sigm(acc[c]);
  if (mode < 2) {
    float ss = acc[0]*acc[0]+acc[1]*acc[1]+acc[2]*acc[2]+acc[3]*acc[3];
    ss += __shfl_xor(ss, 1); ss += __shfl_xor(ss, 2); ss += __shfl_xor(ss, 4);
    ss += __shfl_xor(ss, 8); ss += __shfl_xor(ss, 16);
    float r = rsqrtf(ss + 1e-6f);
    if (mode == 0) r *= SCALE_Q;
    acc[0]*=r; acc[1]*=r; acc[2]*=r; acc[3]*=r;
  }
  size_t o = (size_t)(b*1024 + t)*1024 + c0;
  ushort* Y = (mode==0)?qb16:(mode==1)?kb16:vb16;
  ushort4 yb; yb.x=f2b(acc[0]); yb.y=f2b(acc[1]); yb.z=f2b(acc[2]); yb.w=f2b(acc[3]);
  *(ushort4*)&Y[o] = yb;
}

// -------- per-(b,h) log-decay cumsum, one block per bh --------
__global__ __launch_bounds__(256) void gc2(const float* __restrict__ xs,
    const float* __restrict__ A_log, const float* __restrict__ dt_bias,
    float* __restrict__ gc)
{
  int bh = blockIdx.x, b = bh >> 3, h = bh & 7;
  __shared__ float sc[256];
  int tid = threadIdx.x;
  float aexp = __expf(A_log[h]), db = dt_bias[h];
  int t0 = tid*4;
  float g[4], csum = 0.f;
  #pragma unroll
  for (int z = 0; z < 4; ++z) {
    float zv = xs[(size_t)(b*1024 + t0 + z)*104 + 8 + h] + db;
    float sp = (zv > 20.f) ? zv : log1pf(__expf(zv));
    csum += -aexp*sp;
    g[z] = csum;
  }
  sc[tid] = csum;
  __syncthreads();
  for (int ofs = 1; ofs < 256; ofs <<= 1) {
    float v = (tid >= ofs) ? sc[tid-ofs] : 0.f;
    __syncthreads();
    sc[tid] += v;
    __syncthreads();
  }
  float excl = sc[tid] - csum;
  #pragma unroll
  for (int z = 0; z < 4; ++z) gc[bh*1024 + t0 + z] = excl + g[z];
}

// -------- chunk prep v2: MFMA A-build; bf16 K/V in; emits w f32, -Wk bf16, KpT bf16 --------
__global__ __launch_bounds__(256) void chunk_prep(const ushort* __restrict__ Kg16,
    const ushort* __restrict__ Vg16, const float* __restrict__ xs,
    const float* __restrict__ gcg, float* __restrict__ cw, ushort* __restrict__ cWk16,
    ushort* __restrict__ cKpT16, float* __restrict__ eD)
{
  int blk = blockIdx.x;
  int bh = blk >> 4, ck = blk & 15;
  int b = bh >> 3, h = bh & 7;
  int a = ck << 6;
  __shared__ ushort Kl[64*128];
  __shared__ float As[64][68];
  __shared__ float gcl[65];
  __shared__ float bl[64];
  __shared__ float egc[64];
  __shared__ float edt[64];
  int tid = threadIdx.x;
  int wave = tid >> 6, lane = tid & 63;
  int l15 = lane & 15, kh = lane >> 4;
  for (int e = tid; e < 2048; e += 256) {
    int t = e >> 5;
    int c4u = (e & 31) << 2;
    ushort4 kv = *(const ushort4*)&Kg16[(size_t)(b*1024 + a + t)*1024 + h*128 + c4u];
    unsigned slot = (unsigned)(c4u >> 3) ^ (unsigned)(t & 15);
    *(ushort4*)((char*)Kl + t*256 + slot*16 + (c4u & 7)*2) = kv;
  }
  if (tid < 64) {
    gcl[tid] = gcg[bh*1024 + a + tid];
    bl[tid] = sigm(xs[(size_t)(b*1024 + a + tid)*104 + h]);
  }
  if (tid == 64) gcl[64] = (ck < 15) ? gcg[bh*1024 + a + 64] : 0.f;
  __syncthreads();
  if (tid < 64) {
    egc[tid] = __expf(gcl[tid] - gcl[0]);
    edt[tid] = (ck < 15) ? __expf(gcl[64] - gcl[tid]) : 0.f;
  }
  {
    int arow = wave*16 + l15;
    int asw = arow & 15;
    for (int jt = 0; jt <= wave; ++jt) {
      int brow = jt*16 + l15;
      int bsw = brow & 15;
      f32x4 acc = {0.f,0.f,0.f,0.f};
      #pragma unroll
      for (int ks = 0; ks < 4; ++ks) {
        bf16x8 afr = *(const bf16x8*)((char*)Kl + arow*256 + (((ks*4 + kh) ^ asw) << 4));
        bf16x8 bfr = *(const bf16x8*)((char*)Kl + brow*256 + (((ks*4 + kh) ^ bsw) << 4));
        acc = __builtin_amdgcn_mfma_f32_16x16x32_bf16(afr, bfr, acc, 0, 0, 0);
      }
      int s = jt*16 + l15;
      #pragma unroll
      for (int r = 0; r < 4; ++r) {
        int t = wave*16 + kh*4 + r;
        if (s < t) As[t][s] = bl[t]*acc[r]*__expf(gcl[t]-gcl[s]);
      }
    }
  }
  __syncthreads();
  int c = tid;
  float u[64];
  if (c < 128) {
    #pragma unroll
    for (int t = 0; t < 64; ++t)
      u[t] = bl[t]*b2f(Vg16[(size_t)(b*1024 + a + t)*1024 + h*128 + c]);
  } else {
    int d = c - 128;
    unsigned dslot = (unsigned)(d >> 3);
    #pragma unroll
    for (int t = 0; t < 64; ++t) {
      ushort kv = *(const ushort*)((char*)Kl + t*256 + ((dslot ^ (unsigned)(t & 15)) << 4) + (d & 7)*2);
      u[t] = bl[t]*egc[t]*b2f(kv);
    }
  }
  #pragma unroll
  for (int t = 1; t < 64; ++t) {
    float acc = u[t];
    int s = 0;
    #pragma unroll
    for (; s + 4 <= t; s += 4) {
      float4 a4 = *(float4*)&As[t][s];
      acc -= a4.x*u[s] + a4.y*u[s+1] + a4.z*u[s+2] + a4.w*u[s+3];
    }
    #pragma unroll
    for (; s < t; ++s) acc -= As[t][s]*u[s];
    u[t] = acc;
  }
  size_t cbase = (size_t)blk*8192;
  if (c < 128) {
    #pragma unroll
    for (int t = 0; t < 64; ++t)
      cw[cbase + t*128 + c] = u[t];
  } else {
    int d = c - 128;
    unsigned dslot = (unsigned)(d >> 3);
    #pragma unroll
    for (int t = 0; t < 64; ++t) {
      cWk16[cbase + t*128 + d] = f2b(-u[t]);
      ushort kv = *(const ushort*)((char*)Kl + t*256 + ((dslot ^ (unsigned)(t & 15)) << 4) + (d & 7)*2);
      cKpT16[cbase + d*64 + t] = f2b(b2f(kv)*edt[t]);
    }
  }
  if (tid == 0) eD[blk] = (ck < 15) ? __expf(gcl[64]-gcl[0]) : 0.f;
}

// -------- chunk scan v6: MFMA both phases. 256 blocks = 16 e-slices(8) x 16 bh --------
__global__ __launch_bounds__(256) void chunk_scan6(const float* __restrict__ cw,
    const ushort* __restrict__ cWk16, const ushort* __restrict__ cKpT16,
    const float* __restrict__ eD, ushort* __restrict__ Ut)
{
  int blk = blockIdx.x;
  int slice = blk >> 4, bh = blk & 15;
  int e_base = slice << 3;
  __shared__ ushort Wks[2][8192];
  __shared__ ushort Kps[2][8192];
  __shared__ ushort StT[16*128];
  __shared__ ushort usT[16*64];
  __shared__ float  Stf[128*16];
  int tid = threadIdx.x;
  int wave = tid >> 6, lane = tid & 63;
  int l15 = lane & 15, kh = lane >> 4;
  for (int idx = tid; idx < 16*128; idx += 256) StT[idx] = 0;
  for (int idx = tid; idx < 16*64; idx += 256) usT[idx] = 0;
  for (int idx = tid; idx < 128*16; idx += 256) Stf[idx] = 0.f;

  int e = l15;
  int t0 = wave*16 + kh*4;
  int ci0 = bh << 4;
  f32x4 wcur = {0.f,0.f,0.f,0.f};
  if (e < 8) {
    #pragma unroll
    for (int r = 0; r < 4; ++r)
      wcur[r] = cw[(size_t)ci0*8192 + (t0+r)*128 + e_base + e];
  }
  {
    const char* wg = (const char*)(cWk16 + (size_t)ci0*8192);
    const char* kg = (const char*)(cKpT16 + (size_t)ci0*8192);
    #pragma unroll
    for (int j = 0; j < 4; ++j) {
      unsigned off = (j<<12) + (tid<<4);
      unsigned wrow = off >> 8, wslot = (off >> 4) & 15;
      unsigned wsrc = wrow*256 + ((wslot ^ (wrow & 15)) << 4);
      __builtin_amdgcn_global_load_lds((const __attribute__((address_space(1))) unsigned*)(wg + wsrc),
        (__attribute__((address_space(3))) unsigned*)((char*)&Wks[0][0] + off), 16, 0, 0);
      unsigned krow = off >> 7, kslot = (off >> 4) & 7;
      unsigned ksrc = krow*128 + ((kslot ^ (krow & 7)) << 4);
      __builtin_amdgcn_global_load_lds((const __attribute__((address_space(1))) unsigned*)(kg + ksrc),
        (__attribute__((address_space(3))) unsigned*)((char*)&Kps[0][0] + off), 16, 0, 0);
    }
  }
  __syncthreads();

  for (int i = 0; i < 16; ++i) {
    int ci = ci0 + i, a = i << 6, cur = i & 1;
    f32x4 wnext = {0.f,0.f,0.f,0.f};
    if (i < 15) {
      if (e < 8) {
        #pragma unroll
        for (int r = 0; r < 4; ++r)
          wnext[r] = cw[(size_t)(ci+1)*8192 + (t0+r)*128 + e_base + e];
      }
      const char* wg = (const char*)(cWk16 + (size_t)(ci+1)*8192);
      const char* kg = (const char*)(cKpT16 + (size_t)(ci+1)*8192);
      char* wl = (char*)&Wks[cur^1][0];
      char* kl = (char*)&Kps[cur^1][0];
      #pragma unroll
      for (int j = 0; j < 4; ++j) {
        unsigned off = (j<<12) + (tid<<4);
        unsigned wrow = off >> 8, wslot = (off >> 4) & 15;
        unsigned wsrc = wrow*256 + ((wslot ^ (wrow & 15)) << 4);
        __builtin_amdgcn_global_load_lds((const __attribute__((address_space(1))) unsigned*)(wg + wsrc),
          (__attribute__((address_space(3))) unsigned*)(wl + off), 16, 0, 0);
        unsigned krow = off >> 7, kslot = (off >> 4) & 7;
        unsigned ksrc = krow*128 + ((kslot ^ (krow & 7)) << 4);
        __builtin_amdgcn_global_load_lds((const __attribute__((address_space(1))) unsigned*)(kg + ksrc),
          (__attribute__((address_space(3))) unsigned*)(kl + off), 16, 0, 0);
      }
    }
    {
      f32x4 d = wcur;
      const char* wkb = (const char*)&Wks[cur][0];
      int arow = wave*16 + l15;
      #pragma unroll
      for (int ks = 0; ks < 4; ++ks) {
        bf16x8 afr = *(const bf16x8*)(wkb + arow*256 + (((ks*4 + kh) ^ l15) << 4));
        bf16x8 bfr = *(const bf16x8*)((const char*)StT + l15*256 + (((ks*4 + kh) ^ l15) << 4));
        d = __builtin_amdgcn_mfma_f32_16x16x32_bf16(afr, bfr, d, 0, 0, 0);
      }
      if (e < 8) {
        ushort4 uw;
        uw.x = f2b(d[0]); uw.y = f2b(d[1]); uw.z = f2b(d[2]); uw.w = f2b(d[3]);
        *(ushort4*)((char*)usT + e*128 + (((t0>>3) ^ (e&7)) << 4) + (t0&7)*2) = uw;
        *(ushort4*)&Ut[(size_t)(bh*128 + e_base + e)*1024 + a + t0] = uw;
      }
    }
    asm volatile("s_waitcnt lgkmcnt(0)" ::: "memory");
    __builtin_amdgcn_s_barrier();
    __builtin_amdgcn_sched_barrier(0);
    if (i < 15) {
      float ed = eD[ci];
      const char* kpb = (const char*)&Kps[cur][0];
      #pragma unroll
      for (int mt = 0; mt < 2; ++mt) {
        int krow = (wave*2 + mt)*16 + l15;
        int k0 = (wave*2 + mt)*16 + kh*4;
        f32x4 c;
        #pragma unroll
        for (int r = 0; r < 4; ++r) c[r] = ed * Stf[(k0+r)*16 + e];
        #pragma unroll
        for (int ts = 0; ts < 2; ++ts) {
          bf16x8 afr = *(const bf16x8*)(kpb + krow*128 + (((ts*4 + kh) ^ (krow&7)) << 4));
          bf16x8 bfr = *(const bf16x8*)((const char*)usT + l15*128 + (((ts*4 + kh) ^ (l15&7)) << 4));
          c = __builtin_amdgcn_mfma_f32_16x16x32_bf16(afr, bfr, c, 0, 0, 0);
        }
        #pragma unroll
        for (int r = 0; r < 4; ++r) Stf[(k0+r)*16 + e] = c[r];
        if (e < 8) {
          ushort4 sw;
          sw.x = f2b(c[0]); sw.y = f2b(c[1]); sw.z = f2b(c[2]); sw.w = f2b(c[3]);
          *(ushort4*)((char*)StT + e*256 + (((k0>>3) ^ e) << 4) + (k0&7)*2) = sw;
        }
      }
      wcur = wnext;
      asm volatile("s_waitcnt vmcnt(0) lgkmcnt(0)" ::: "memory");
      __builtin_amdgcn_s_barrier();
      __builtin_amdgcn_sched_barrier(0);
    }
  }
}

// -------- MFMA log-linear readout v3: LDS-staged K/Ut, double-buffered --------
__global__ __launch_bounds__(256) void readout3(const ushort* __restrict__ Qb,
    const ushort* __restrict__ Kb, const ushort* __restrict__ Ut,
    const float* __restrict__ gcg, const float* __restrict__ xs,
    float* __restrict__ Og)
{
  int blk = blockIdx.x;
  int bh = blk >> 4, ic = blk & 15;
  int half = blockIdx.y;
  int b = bh >> 3, h = bh & 7;
  int tbase = ic << 6;
  __shared__ ushort Ks[2][8192];
  __shared__ ushort Us[2][8192];
  __shared__ ushort Pl[4][1024];
  __shared__ float lamS[64][12];
  int tid = threadIdx.x;
  int wave = tid >> 6, lane = tid & 63;
  int l15 = lane & 15, kh = lane >> 4;

  const char* kgb = (const char*)Kb + ((size_t)(b*1024)*1024 + h*128)*2;
  const char* ugb = (const char*)Ut + ((size_t)(bh*128)*1024)*2;

  for (int e = tid; e < 64*11; e += 256) {
    int t = e/11, l = e%11;
    lamS[t][l] = sigm(xs[(size_t)(b*1024+tbase+t)*104 + 16 + h*11 + l]);
  }
  int tl = kh*4;
  float gct_r[4];
  #pragma unroll
  for (int r = 0; r < 4; ++r) gct_r[r] = gcg[bh*1024 + tbase + wave*16 + tl + r];
  bf16x8 qf[4];
  {
    const ushort* qp = &Qb[(size_t)(b*1024 + tbase + wave*16 + l15)*1024 + h*128 + kh*8];
    #pragma unroll
    for (int kk = 0; kk < 4; ++kk) qf[kk] = *(const bf16x8*)(qp + kk*32);
  }

  f32x4 accO[8] = {};
  int nsteps = ic + 1;
  int jmid = (nsteps + 1) >> 1;
  int j0 = half ? jmid : 0;
  int j1 = half ? nsteps : jmid;
  ushort* Pw = &Pl[wave][0];

  if (j0 < j1) {
    {
      const char* kg = kgb + (size_t)(j0<<6)*2048;
      const char* ug = ugb + (size_t)(j0<<6)*2;
      #pragma unroll
      for (int it = 0; it < 4; ++it) {
        unsigned off = (it<<12) + (tid<<4);
        unsigned krow = off >> 8, kc = (off >> 4) & 15;
        unsigned ksrc = krow*2048 + ((kc ^ (krow & 15)) << 4);
        __builtin_amdgcn_global_load_lds((const __attribute__((address_space(1))) unsigned*)(kg + ksrc),
          (__attribute__((address_space(3))) unsigned*)((char*)&Ks[0][0] + off), 16, 0, 0);
        unsigned ud = off >> 7, uc = (off >> 4) & 7;
        unsigned usrc = ud*2048 + ((uc ^ (ud & 7)) << 4);
        __builtin_amdgcn_global_load_lds((const __attribute__((address_space(1))) unsigned*)(ug + usrc),
          (__attribute__((address_space(3))) unsigned*)((char*)&Us[0][0] + off), 16, 0, 0);
      }
    }
    __syncthreads();
    int cur = 0;
    for (int j = j0; j < j1; ++j) {
      int sbase = j << 6;
      if (j + 1 < j1) {
        const char* kg = kgb + (size_t)((j+1)<<6)*2048;
        const char* ug = ugb + (size_t)((j+1)<<6)*2;
        char* kl = (char*)&Ks[cur^1][0];
        char* ul = (char*)&Us[cur^1][0];
        #pragma unroll
        for (int it = 0; it < 4; ++it) {
          unsigned off = (it<<12) + (tid<<4);
          unsigned krow = off >> 8, kc = (off >> 4) & 15;
          unsigned ksrc = krow*2048 + ((kc ^ (krow & 15)) << 4);
          __builtin_amdgcn_global_load_lds((const __attribute__((address_space(1))) unsigned*)(kg + ksrc),
            (__attribute__((address_space(3))) unsigned*)(kl + off), 16, 0, 0);
          unsigned ud = off >> 7, uc = (off >> 4) & 7;
          unsigned usrc = ud*2048 + ((uc ^ (ud & 7)) << 4);
          __builtin_amdgcn_global_load_lds((const __attribute__((address_space(1))) unsigned*)(ug + usrc),
            (__attribute__((address_space(3))) unsigned*)(ul + off), 16, 0, 0);
        }
      }
      float gcs_r[4];
      #pragma unroll
      for (int jt = 0; jt < 4; ++jt)
        gcs_r[jt] = gcg[bh*1024 + sbase + jt*16 + l15];
      f32x4 accS[4] = {};
      const char* ksb = (const char*)&Ks[cur][0];
      #pragma unroll
      for (int jt = 0; jt < 4; ++jt) {
        int row = jt*16 + l15;
        int rsw = row & 15;
        #pragma unroll
        for (int kk = 0; kk < 4; ++kk) {
          bf16x8 kf = *(const bf16x8*)(ksb + row*256 + (((kk*4 + kh) ^ rsw) << 4));
          accS[jt] = __builtin_amdgcn_mfma_f32_16x16x32_bf16(qf[kk], kf, accS[jt], 0, 0, 0);
        }
      }
      #pragma unroll
      for (int jt = 0; jt < 4; ++jt) {
        int sg = sbase + jt*16 + l15;
        #pragma unroll
        for (int r = 0; r < 4; ++r) {
          int t_loc = tl + r;
          int tg = tbase + wave*16 + t_loc;
          float pv = 0.f;
          if (sg <= tg) {
            int lev = 31 - __clz((unsigned)((tg+1) ^ sg));
            lev = lev > 10 ? 10 : lev;
            pv = accS[jt][r] * __expf(gct_r[r] - gcs_r[jt]) * lamS[wave*16 + t_loc][lev];
          }
          int bo = (t_loc << 7) + ((jt*16 + l15) << 1);
          bo ^= (t_loc & 7) << 4;
          *(ushort*)((char*)Pw + bo) = f2b(pv);
        }
      }
      const char* usb = (const char*)&Us[cur][0];
      #pragma unroll
      for (int ks = 0; ks < 2; ++ks) {
        int bo = (l15 << 7) + ((ks*32 + kh*8) << 1);
        bo ^= (l15 & 7) << 4;
        bf16x8 pa = *(bf16x8*)((char*)Pw + bo);
        #pragma unroll
        for (int dt = 0; dt < 8; ++dt) {
          int d = dt*16 + l15;
          bf16x8 uf = *(const bf16x8*)(usb + d*128 + (((ks*4 + kh) ^ (d & 7)) << 4));
          accO[dt] = __builtin_amdgcn_mfma_f32_16x16x32_bf16(pa, uf, accO[dt], 0, 0, 0);
        }
      }
      __syncthreads();
      cur ^= 1;
    }
  }
  float* og = Og + (size_t)half*2097152;
  #pragma unroll
  for (int dt = 0; dt < 8; ++dt) {
    #pragma unroll
    for (int r = 0; r < 4; ++r) {
      int row = tbase + wave*16 + tl + r;
      og[(size_t)(b*1024 + row)*1024 + h*128 + dt*16 + l15] = accO[dt][r];
    }
  }
}

// -------- gated RMSNorm (sums two partial O buffers), bf16 gate -> bf16 out --------
// 256 threads = 4 waves, each wave one (t,h) row
__global__ __launch_bounds__(256) void normgate(const float* __restrict__ O1,
    const float* __restrict__ O2, const ushort* __restrict__ G16,
    const float* __restrict__ norm_w, ushort* __restrict__ Y)
{
  int row = blockIdx.x*4 + (threadIdx.x >> 6);
  int lane = threadIdx.x & 63;
  size_t base = (size_t)(row >> 3)*1024 + (size_t)(row & 7)*128;
  float2 oa = *(const float2*)&O1[base + lane*2];
  float2 ob = *(const float2*)&O2[base + lane*2];
  float ox = oa.x + ob.x, oy = oa.y + ob.y;
  float ss = ox*ox + oy*oy;
  #pragma unroll
  for (int m = 1; m < 64; m <<= 1) ss += __shfl_xor(ss, m);
  float r = rsqrtf(ss * (1.f/128.f) + 1e-5f);
  ushort2 g16 = *(const ushort2*)&G16[base + lane*2];
  float gx = b2f(g16.x), gy = b2f(g16.y);
  ushort2 y;
  y.x = f2b(ox * r * norm_w[lane*2+0] * (gx * sigm(gx)));
  y.y = f2b(oy * r * norm_w[lane*2+1] * (gy * sigm(gy)));
  *(ushort2*)&Y[base + lane*2] = y;
}

extern "C" void kernel_launch(void* const* d_in, const int* in_sizes, int n_in,
                              void* d_out, int out_size, void* d_ws, size_t ws_size,
                              hipStream_t stream)
{
  const float* x    = (const float*)d_in[0];
  const float* Wq   = (const float*)d_in[3];
  const float* Wk   = (const float*)d_in[4];
  const float* Wv   = (const float*)d_in[5];
  const float* Wb   = (const float*)d_in[6];
  const float* Wa   = (const float*)d_in[7];
  const float* Wl   = (const float*)d_in[8];
  const float* Wg   = (const float*)d_in[9];
  const float* Wo   = (const float*)d_in[10];
  const float* cq   = (const float*)d_in[11];
  const float* ck   = (const float*)d_in[12];
  const float* cv   = (const float*)d_in[13];
  const float* A_log   = (const float*)d_in[14];
  const float* dt_bias = (const float*)d_in[15];
  const float* norm_w  = (const float*)d_in[16];
  float* out = (float*)d_out;

  float* p = (float*)d_ws;
  float* xqkv = p;  p += 6291456;
  float* xg   = p;  p += 2097152;
  float* kbu  = p;  p += 2097152;
  float* vbu  = p;  p += 2097152;
  float* o1   = p;  p += 2097152;            // o1,o2 MUST be adjacent (readout3 half offset)
  float* o2   = p;  p += 2097152;
  float* xs   = p;  p += 212992;
  float* gc   = p;  p += 16384;
  float* eD   = p;  p += 256;
  ushort* x16 = (ushort*)p; p += 1048576;
  ushort* Wt4 = (ushort*)p; p += 2097152;
  ushort* Wot = (ushort*)p; p += 524288;
  float* Wsm  = p;  p += 106496;
  ushort* yb16= (ushort*)p; p += 1048576;
  ushort* qb16= (ushort*)p; p += 1048576;
  ushort* kb16= (ushort*)p; p += 1048576;
  ushort* ut16= (ushort*)p; p += 1048576;
  ushort* xqkv16 = (ushort*)xqkv;
  ushort* xg16 = (ushort*)xg;                // [2048][1024] bf16 gate
  ushort* vb16 = (ushort*)vbu;
  float* cw  = xqkv;
  ushort* cWk16  = (ushort*)(xqkv + 2097152);
  ushort* cKpT16 = (ushort*)(xqkv + 3145728);
  float* part = o1;
  (void)kbu;

  dim3 blk(256);
  prep_all<<<dim3(32,32,8), blk, 0, stream>>>(Wq, Wk, Wv, Wg, Wo, x, Wb, Wa, Wl,
                                              Wt4, Wot, x16, Wsm);
  gemm_bf16<<<dim3(32,16), blk, 0, stream>>>(x16, Wt4, xqkv16, xg16, 2048, 4096, 1024,
                                             3072, 3072, 1024, 1, 1);
  skinny104<<<dim3(32,8), blk, 0, stream>>>(x, Wsm, part);
  reduce8<<<dim3(833), blk, 0, stream>>>(part, xs);
  conv_fused<<<dim3(2048,3), blk, 0, stream>>>(xqkv16, cq, ck, cv, qb16, kb16, vb16, 3072);
  gc2<<<dim3(16), blk, 0, stream>>>(xs, A_log, dt_bias, gc);
  chunk_prep<<<dim3(256), blk, 0, stream>>>(kb16, vb16, xs, gc, cw, cWk16, cKpT16, eD);
  chunk_scan6<<<dim3(256), blk, 0, stream>>>(cw, cWk16, cKpT16, eD, ut16);
  readout3<<<dim3(256,2), blk, 0, stream>>>(qb16, kb16, ut16, gc, xs, o1);
  normgate<<<dim3(4096), blk, 0, stream>>>(o1, o2, xg16, norm_w, yb16);
  gemm_wo64<<<dim3(8,32), dim3(128), 0, stream>>>(yb16, Wot, out, 1024);
}